// Round 1
// baseline (8754.688 us; speedup 1.0000x reference)
//
#include <hip/hip_runtime.h>
#include <math.h>
#include <cstddef>

// ---------------------------------------------------------------------------
// Workspace layout (float offsets). Total need: 83,894,272 floats = 335.6 MB.
//   res_xp : [64][4096][256]  res_x in patch-major layout
//            res_xp[ci*1048576 + s*256 + (ky*16+kx)] = res_x[ci, y*16+ky, x*16+kx], s=y*64+x
//   P      : [4096][4096]     res_x_base transposed: P[s*4096 + co]
//   b_buf  : [4][16][16][4]   b
//   b_rot  : [4][16][16][4]   rope(l2norm(b))
// ---------------------------------------------------------------------------
#define RES_XP_F 0ull
#define P_F      67108864ull
#define BBUF_F   83886080ull
#define BROT_F   83890176ull
#define ATTN_OFF 16777216ull   // x_final elements before attn in d_out

// ===========================================================================
// Kernel 1: x_feat conv (3->64, 3x3, pad1, 8x8) + b-chain (LN, proj, l2, rope)
// ===========================================================================
__global__ __launch_bounds__(256) void k_bchain(
    const float* __restrict__ x, const float* __restrict__ xcw, const float* __restrict__ xcb,
    const float* __restrict__ bpw, const float* __restrict__ bpb,
    const float* __restrict__ nbg, const float* __restrict__ nbb,
    float* __restrict__ b_buf, float* __restrict__ b_rot)
{
    __shared__ float xs[3][8][8];
    __shared__ float xf[64][8][8];
    int t = threadIdx.x;
    if (t < 192) xs[t / 64][(t / 8) % 8][t % 8] = x[t];
    __syncthreads();
    for (int o = t; o < 4096; o += 256) {
        int c = o >> 6, i = (o >> 3) & 7, j = o & 7;
        float acc = xcb[c];
        for (int ic = 0; ic < 3; ++ic)
            for (int ky = 0; ky < 3; ++ky)
                for (int kx = 0; kx < 3; ++kx) {
                    int ii = i - 1 + ky, jj = j - 1 + kx;
                    if (ii >= 0 && ii < 8 && jj >= 0 && jj < 8)
                        acc = fmaf(xs[ic][ii][jj], xcw[((c * 3 + ic) * 3 + ky) * 3 + kx], acc);
                }
        xf[c][i][j] = acc;
    }
    __syncthreads();
    for (int idx = t; idx < 1024; idx += 256) {
        int wi = idx >> 8, h = (idx >> 4) & 15, pp = idx & 15;
        int pr = pp >> 2, pc = pp & 3;
        int gi = 4 * (wi >> 1) + pr, gj = 4 * (wi & 1) + pc;
        float v[4];
        #pragma unroll
        for (int d = 0; d < 4; ++d) v[d] = xf[h * 4 + d][gi][gj];
        float mu = 0.25f * (v[0] + v[1] + v[2] + v[3]);
        float var = 0.25f * ((v[0]-mu)*(v[0]-mu) + (v[1]-mu)*(v[1]-mu) +
                             (v[2]-mu)*(v[2]-mu) + (v[3]-mu)*(v[3]-mu));
        float inv = rsqrtf(var + 1e-5f);
        float xh[4];
        #pragma unroll
        for (int d = 0; d < 4; ++d) xh[d] = (v[d] - mu) * inv * nbg[d] + nbb[d];
        float bv[4];
        #pragma unroll
        for (int d = 0; d < 4; ++d) {
            float a = bpb[d];
            #pragma unroll
            for (int e = 0; e < 4; ++e) a = fmaf(xh[e], bpw[d * 4 + e], a);
            bv[d] = a;
        }
        #pragma unroll
        for (int d = 0; d < 4; ++d) b_buf[idx * 4 + d] = bv[d];
        float nn = sqrtf(bv[0]*bv[0] + bv[1]*bv[1] + bv[2]*bv[2] + bv[3]*bv[3]);
        float in2 = 1.0f / fmaxf(nn, 1e-12f);
        float bn[4];
        #pragma unroll
        for (int d = 0; d < 4; ++d) bn[d] = bv[d] * in2;
        float s0, c0, s1, c1;
        sincosf((float)pr, &s0, &c0);
        sincosf((float)pc, &s1, &c1);
        b_rot[idx * 4 + 0] = bn[0] * c0 - bn[1] * s0;
        b_rot[idx * 4 + 1] = bn[0] * s0 + bn[1] * c0;
        b_rot[idx * 4 + 2] = bn[2] * c1 - bn[3] * s1;
        b_rot[idx * 4 + 3] = bn[2] * s1 + bn[3] * c1;
    }
}

// ===========================================================================
// Kernel 2: fused bilinear resize (8x8 -> 1024x1024) + 3x3 conv (3->64, pad1),
// writing res_x in patch-major layout. One block per 16x16 output patch.
// ===========================================================================
__global__ __launch_bounds__(256) void k_resconv(
    const float* __restrict__ x, const float* __restrict__ rcw, const float* __restrict__ rcb,
    float* __restrict__ res_xp)
{
    __shared__ float xs[3][8][8];
    __shared__ float wsm[1728];       // [64][3][3][3]
    __shared__ float rs[3][18][18];   // resized halo tile
    int t = threadIdx.x;
    if (t < 192) xs[t / 64][(t / 8) % 8][t % 8] = x[t];
    for (int i = t; i < 1728; i += 256) wsm[i] = rcw[i];
    int py = blockIdx.x >> 6, px = blockIdx.x & 63;
    int Y0 = py * 16, X0 = px * 16;
    __syncthreads();
    for (int o = t; o < 972; o += 256) {
        int ic = o / 324, rr = (o / 18) % 18, cc = o % 18;
        int u = Y0 - 1 + rr, v = X0 - 1 + cc;
        float val = 0.0f;
        if (u >= 0 && u < 1024 && v >= 0 && v < 1024) {
            float fu = (u + 0.5f) * 0.0078125f - 0.5f;
            float fv = (v + 0.5f) * 0.0078125f - 0.5f;
            float fi = floorf(fu), fj = floorf(fv);
            float tu = fu - fi, tv = fv - fj;
            int i0 = (int)fi, j0 = (int)fj;
            int i0c = min(max(i0, 0), 7), i1c = min(max(i0 + 1, 0), 7);
            int j0c = min(max(j0, 0), 7), j1c = min(max(j0 + 1, 0), 7);
            float a00 = xs[ic][i0c][j0c], a01 = xs[ic][i0c][j1c];
            float a10 = xs[ic][i1c][j0c], a11 = xs[ic][i1c][j1c];
            val = (a00 * (1.f - tv) + a01 * tv) * (1.f - tu)
                + (a10 * (1.f - tv) + a11 * tv) * tu;
        }
        rs[ic][rr][cc] = val;
    }
    __syncthreads();
    int ly = t >> 4, lx = t & 15;
    float rv[3][3][3];
    #pragma unroll
    for (int ic = 0; ic < 3; ++ic)
        #pragma unroll
        for (int ky = 0; ky < 3; ++ky)
            #pragma unroll
            for (int kx = 0; kx < 3; ++kx)
                rv[ic][ky][kx] = rs[ic][ly + ky][lx + kx];
    size_t sbase = (size_t)blockIdx.x * 256 + t;
    for (int c = 0; c < 64; ++c) {
        float acc = rcb[c];
        const float* wp = &wsm[c * 27];
        #pragma unroll
        for (int ic = 0; ic < 3; ++ic)
            #pragma unroll
            for (int ky = 0; ky < 3; ++ky)
                #pragma unroll
                for (int kx = 0; kx < 3; ++kx)
                    acc = fmaf(rv[ic][ky][kx], wp[ic * 9 + ky * 3 + kx], acc);
        res_xp[(size_t)c * 1048576 + sbase] = acc;
    }
}

// ===========================================================================
// Kernel 3/5: NT GEMM. C[m*N+n] = bias + sum_k A[m,k]*B[n,k]
//   AMODE 0: A row-major, lda
//   AMODE 1: A = im2col of res_xp: A[m,k] = res_xp[(k>>8)*1048576 + m*256 + (k&255)]
// B row-major with ldb. biasPerRow: bias[m] else bias[n].
// 128x128x16 tile, 256 threads, 8x8 micro-tile.
// ===========================================================================
template <int AMODE>
__global__ __launch_bounds__(256) void gemm_nt(
    const float* __restrict__ A, const float* __restrict__ B,
    const float* __restrict__ bias, float* __restrict__ C,
    int M, int N, int K, int lda, int ldb, int biasPerRow)
{
    constexpr int BK = 16;
    __shared__ float As[BK][128];
    __shared__ float Bs[BK][128];
    int m0 = blockIdx.y * 128, n0 = blockIdx.x * 128;
    int t = threadIdx.x;
    int tx = t & 15, ty = t >> 4;
    int q = t & 3, rr = t >> 2;
    float acc[8][8] = {};
    for (int k0 = 0; k0 < K; k0 += BK) {
        #pragma unroll
        for (int hh = 0; hh < 2; ++hh) {
            int m = rr + hh * 64;
            size_t aoff;
            if (AMODE == 1) {
                int k = k0 + q * 4;
                aoff = (size_t)(k >> 8) * 1048576 + (size_t)(m0 + m) * 256 + (k & 255);
            } else {
                aoff = (size_t)(m0 + m) * lda + (k0 + q * 4);
            }
            float4 av = *(const float4*)(A + aoff);
            As[q * 4 + 0][m] = av.x; As[q * 4 + 1][m] = av.y;
            As[q * 4 + 2][m] = av.z; As[q * 4 + 3][m] = av.w;
            float4 bv = *(const float4*)(B + (size_t)(n0 + m) * ldb + (k0 + q * 4));
            Bs[q * 4 + 0][m] = bv.x; Bs[q * 4 + 1][m] = bv.y;
            Bs[q * 4 + 2][m] = bv.z; Bs[q * 4 + 3][m] = bv.w;
        }
        __syncthreads();
        #pragma unroll
        for (int kk = 0; kk < BK; ++kk) {
            float4 a0 = *(const float4*)&As[kk][ty * 8];
            float4 a1 = *(const float4*)&As[kk][ty * 8 + 4];
            float4 b0 = *(const float4*)&Bs[kk][tx * 8];
            float4 b1 = *(const float4*)&Bs[kk][tx * 8 + 4];
            float a[8] = {a0.x, a0.y, a0.z, a0.w, a1.x, a1.y, a1.z, a1.w};
            float b[8] = {b0.x, b0.y, b0.z, b0.w, b1.x, b1.y, b1.z, b1.w};
            #pragma unroll
            for (int i = 0; i < 8; ++i)
                #pragma unroll
                for (int j = 0; j < 8; ++j)
                    acc[i][j] = fmaf(a[i], b[j], acc[i][j]);
        }
        __syncthreads();
    }
    #pragma unroll
    for (int i = 0; i < 8; ++i) {
        int m = m0 + ty * 8 + i;
        float rowb = biasPerRow ? bias[m] : 0.0f;
        #pragma unroll
        for (int jq = 0; jq < 2; ++jq) {
            int n = n0 + tx * 8 + jq * 4;
            float4 v;
            v.x = acc[i][jq * 4 + 0] + (biasPerRow ? rowb : bias[n + 0]);
            v.y = acc[i][jq * 4 + 1] + (biasPerRow ? rowb : bias[n + 1]);
            v.z = acc[i][jq * 4 + 2] + (biasPerRow ? rowb : bias[n + 2]);
            v.w = acc[i][jq * 4 + 3] + (biasPerRow ? rowb : bias[n + 3]);
            *(float4*)(C + (size_t)m * N + n) = v;
        }
    }
}

// ===========================================================================
// Kernel 4: fused q-chain + attn + out_win; updates P in place with residual.
// One thread per (wi,h,p) row. blockIdx.y = wi*16+h, blockIdx.x = p chunk.
// ===========================================================================
__global__ __launch_bounds__(256) void k_attn(
    float* __restrict__ P, const float* __restrict__ b_buf, const float* __restrict__ b_rot,
    const float* __restrict__ qpw, const float* __restrict__ qpb,
    const float* __restrict__ nqg, const float* __restrict__ nqb,
    const float* __restrict__ qaw, const float* __restrict__ qab,
    const float* __restrict__ pos, float* __restrict__ attn_out)
{
    __shared__ float bs[16][4], brs[16][4];
    int t = threadIdx.x;
    int wh = blockIdx.y;
    int wi = wh >> 4, h = wh & 15;
    if (t < 64) {
        ((float*)bs)[t]  = b_buf[wh * 64 + t];
        ((float*)brs)[t] = b_rot[wh * 64 + t];
    }
    __syncthreads();
    int p = blockIdx.x * 256 + t;
    int wr = p >> 8, wc = p & 255;
    int gr = ((wi >> 1) << 8) + wr, gc = ((wi & 1) << 8) + wc;
    int y = gr >> 3, hnr = gr & 7, xq = gc >> 3, wnr = gc & 7;
    size_t base = (size_t)(y * 64 + xq) * 4096 + h * 256 + hnr * 8 + wnr;
    float r[4];
    #pragma unroll
    for (int d = 0; d < 4; ++d) r[d] = P[base + (size_t)d * 64];
    // LayerNorm (norm_q)
    float mu = 0.25f * (r[0] + r[1] + r[2] + r[3]);
    float var = 0.25f * ((r[0]-mu)*(r[0]-mu) + (r[1]-mu)*(r[1]-mu) +
                         (r[2]-mu)*(r[2]-mu) + (r[3]-mu)*(r[3]-mu));
    float inv = rsqrtf(var + 1e-5f);
    float xh[4];
    #pragma unroll
    for (int d = 0; d < 4; ++d) xh[d] = (r[d] - mu) * inv * nqg[d] + nqb[d];
    // q projection
    float q4[4];
    #pragma unroll
    for (int d = 0; d < 4; ++d) {
        float a = qpb[d];
        #pragma unroll
        for (int e = 0; e < 4; ++e) a = fmaf(xh[e], qpw[d * 4 + e], a);
        q4[d] = a;
    }
    // gate
    float z = qab[0];
    #pragma unroll
    for (int d = 0; d < 4; ++d) z = fmaf(q4[d], qaw[d], z);
    float gate = 1.0f / (1.0f + expf(-z));
    // mix with pos, l2norm
    float4 pv = *(const float4*)(pos + ((size_t)h * 65536 + p) * 4);
    float v[4];
    v[0] = q4[0] * gate + pv.x * (1.0f - gate);
    v[1] = q4[1] * gate + pv.y * (1.0f - gate);
    v[2] = q4[2] * gate + pv.z * (1.0f - gate);
    v[3] = q4[3] * gate + pv.w * (1.0f - gate);
    float nn = sqrtf(v[0]*v[0] + v[1]*v[1] + v[2]*v[2] + v[3]*v[3]);
    float in2 = 1.0f / fmaxf(nn, 1e-12f);
    #pragma unroll
    for (int d = 0; d < 4; ++d) v[d] *= in2;
    // rope (window-local coords)
    float s0, c0, s1, c1;
    sincosf((float)wr, &s0, &c0);
    sincosf((float)wc, &s1, &c1);
    float qr[4];
    qr[0] = v[0] * c0 - v[1] * s0;
    qr[1] = v[0] * s0 + v[1] * c0;
    qr[2] = v[2] * c1 - v[3] * s1;
    qr[3] = v[2] * s1 + v[3] * c1;
    // attn row + out row
    float arow[16];
    #pragma unroll
    for (int k = 0; k < 16; ++k)
        arow[k] = qr[0] * brs[k][0] + qr[1] * brs[k][1] + qr[2] * brs[k][2] + qr[3] * brs[k][3];
    size_t abase = ((size_t)wh * 65536 + p) * 16;
    #pragma unroll
    for (int kq = 0; kq < 4; ++kq) {
        float4 av;
        av.x = arow[kq * 4 + 0]; av.y = arow[kq * 4 + 1];
        av.z = arow[kq * 4 + 2]; av.w = arow[kq * 4 + 3];
        *(float4*)(attn_out + abase + kq * 4) = av;
    }
    float o[4] = {0.f, 0.f, 0.f, 0.f};
    #pragma unroll
    for (int k = 0; k < 16; ++k) {
        #pragma unroll
        for (int d = 0; d < 4; ++d) o[d] = fmaf(arow[k], bs[k][d], o[d]);
    }
    #pragma unroll
    for (int d = 0; d < 4; ++d) P[base + (size_t)d * 64] = r[d] + o[d];
}

// ===========================================================================
extern "C" void kernel_launch(void* const* d_in, const int* in_sizes, int n_in,
                              void* d_out, int out_size, void* d_ws, size_t ws_size,
                              hipStream_t stream)
{
    (void)in_sizes; (void)n_in; (void)out_size; (void)ws_size;
    const float* x    = (const float*)d_in[0];
    const float* xcw  = (const float*)d_in[1];
    const float* xcb  = (const float*)d_in[2];
    const float* rcw  = (const float*)d_in[3];
    const float* rcb  = (const float*)d_in[4];
    const float* pw   = (const float*)d_in[5];
    const float* pb   = (const float*)d_in[6];
    const float* bpw  = (const float*)d_in[7];
    const float* bpb  = (const float*)d_in[8];
    const float* qpw  = (const float*)d_in[9];
    const float* qpb  = (const float*)d_in[10];
    const float* nbg  = (const float*)d_in[11];
    const float* nbb  = (const float*)d_in[12];
    const float* nqg  = (const float*)d_in[13];
    const float* nqb  = (const float*)d_in[14];
    const float* qaw  = (const float*)d_in[15];
    const float* qab  = (const float*)d_in[16];
    const float* pos  = (const float*)d_in[17];
    const float* prw  = (const float*)d_in[18];
    const float* prb  = (const float*)d_in[19];

    float* ws     = (float*)d_ws;
    float* res_xp = ws + RES_XP_F;
    float* P      = ws + P_F;
    float* b_buf  = ws + BBUF_F;
    float* b_rot  = ws + BROT_F;
    float* out    = (float*)d_out;

    k_bchain<<<1, 256, 0, stream>>>(x, xcw, xcb, bpw, bpb, nbg, nbb, b_buf, b_rot);
    k_resconv<<<4096, 256, 0, stream>>>(x, rcw, rcb, res_xp);
    // patch conv as GEMM: M = s (4096), N = co (4096), K = 16384; C = P[s,co]
    gemm_nt<1><<<dim3(32, 32), 256, 0, stream>>>(res_xp, pw, pb, P,
                                                 4096, 4096, 16384, 0, 16384, 0);
    // fused q-chain / attn / out_win (+ residual into P)
    k_attn<<<dim3(256, 64), 256, 0, stream>>>(P, b_buf, b_rot, qpw, qpb, nqg, nqb,
                                              qaw, qab, pos, out + ATTN_OFF);
    // 1x1 proj conv as GEMM: M = co, N = s, K = ci (4096); C = x_final[co,s]
    gemm_nt<0><<<dim3(32, 32), 256, 0, stream>>>(prw, P, prb, out,
                                                 4096, 4096, 4096, 4096, 4096, 1);
}

// Round 2
// 1288.889 us; speedup vs baseline: 6.7924x; 6.7924x over previous
//
#include <hip/hip_runtime.h>
#include <hip/hip_bf16.h>
#include <math.h>
#include <cstddef>

// ---------------------------------------------------------------------------
// Workspace layout. Peak 335.6 MB (same as round 0).
//   Abf  : bf16 [4096][16384]  patch-GEMM A operand (resize+conv, K-contig)
//          shorts [0 .. 67108864)            = float offset [0 .. 33554432)
//   pwb  : bf16 [4096][16384]  patch_w cast
//          shorts [67108864 .. 134217728)    = float offset [33554432 .. 67108864)
//   P    : f32  [4096 s][4096 co]  res_x_base (then +attn residual in place)
//          float offset [67108864 .. 83886080)
//   b_buf/b_rot : float offset 83886080 / 83890176
//   After patch GEMM, Abf/pwb are dead; reuse:
//   Pb   : bf16 [4096][4096]  shorts [0 .. 16777216)
//   prwb : bf16 [4096][4096]  shorts [33554432 .. 50331648)
// ---------------------------------------------------------------------------
#define P_F      67108864ull
#define BBUF_F   83886080ull
#define BROT_F   83890176ull
#define ATTN_OFF 16777216ull   // x_final elements before attn in d_out

typedef __attribute__((ext_vector_type(8))) short bf16x8;
typedef __attribute__((ext_vector_type(4))) float f32x4;

#define GLOAD16(gsrc, ldst) \
  __builtin_amdgcn_global_load_lds((const __attribute__((address_space(1))) void*)(gsrc), \
                                   (__attribute__((address_space(3))) void*)(ldst), 16, 0, 0)

// ===========================================================================
// Kernel 1: x_feat conv (3->64, 3x3, pad1, 8x8) + b-chain (LN, proj, l2, rope)
// ===========================================================================
__global__ __launch_bounds__(256) void k_bchain(
    const float* __restrict__ x, const float* __restrict__ xcw, const float* __restrict__ xcb,
    const float* __restrict__ bpw, const float* __restrict__ bpb,
    const float* __restrict__ nbg, const float* __restrict__ nbb,
    float* __restrict__ b_buf, float* __restrict__ b_rot)
{
    __shared__ float xs[3][8][8];
    __shared__ float xf[64][8][8];
    int t = threadIdx.x;
    if (t < 192) xs[t / 64][(t / 8) % 8][t % 8] = x[t];
    __syncthreads();
    for (int o = t; o < 4096; o += 256) {
        int c = o >> 6, i = (o >> 3) & 7, j = o & 7;
        float acc = xcb[c];
        for (int ic = 0; ic < 3; ++ic)
            for (int ky = 0; ky < 3; ++ky)
                for (int kx = 0; kx < 3; ++kx) {
                    int ii = i - 1 + ky, jj = j - 1 + kx;
                    if (ii >= 0 && ii < 8 && jj >= 0 && jj < 8)
                        acc = fmaf(xs[ic][ii][jj], xcw[((c * 3 + ic) * 3 + ky) * 3 + kx], acc);
                }
        xf[c][i][j] = acc;
    }
    __syncthreads();
    for (int idx = t; idx < 1024; idx += 256) {
        int wi = idx >> 8, h = (idx >> 4) & 15, pp = idx & 15;
        int pr = pp >> 2, pc = pp & 3;
        int gi = 4 * (wi >> 1) + pr, gj = 4 * (wi & 1) + pc;
        float v[4];
        #pragma unroll
        for (int d = 0; d < 4; ++d) v[d] = xf[h * 4 + d][gi][gj];
        float mu = 0.25f * (v[0] + v[1] + v[2] + v[3]);
        float var = 0.25f * ((v[0]-mu)*(v[0]-mu) + (v[1]-mu)*(v[1]-mu) +
                             (v[2]-mu)*(v[2]-mu) + (v[3]-mu)*(v[3]-mu));
        float inv = rsqrtf(var + 1e-5f);
        float xh[4];
        #pragma unroll
        for (int d = 0; d < 4; ++d) xh[d] = (v[d] - mu) * inv * nbg[d] + nbb[d];
        float bv[4];
        #pragma unroll
        for (int d = 0; d < 4; ++d) {
            float a = bpb[d];
            #pragma unroll
            for (int e = 0; e < 4; ++e) a = fmaf(xh[e], bpw[d * 4 + e], a);
            bv[d] = a;
        }
        #pragma unroll
        for (int d = 0; d < 4; ++d) b_buf[idx * 4 + d] = bv[d];
        float nn = sqrtf(bv[0]*bv[0] + bv[1]*bv[1] + bv[2]*bv[2] + bv[3]*bv[3]);
        float in2 = 1.0f / fmaxf(nn, 1e-12f);
        float bn[4];
        #pragma unroll
        for (int d = 0; d < 4; ++d) bn[d] = bv[d] * in2;
        float s0, c0, s1, c1;
        sincosf((float)pr, &s0, &c0);
        sincosf((float)pc, &s1, &c1);
        b_rot[idx * 4 + 0] = bn[0] * c0 - bn[1] * s0;
        b_rot[idx * 4 + 1] = bn[0] * s0 + bn[1] * c0;
        b_rot[idx * 4 + 2] = bn[2] * c1 - bn[3] * s1;
        b_rot[idx * 4 + 3] = bn[2] * s1 + bn[3] * c1;
    }
}

// ===========================================================================
// Kernel 2: fused bilinear resize (8x8 -> 1024x1024) + 3x3 conv (3->64, pad1),
// writing the patch-GEMM A operand in bf16, [s=patch][k=c*256+ky*16+kx].
// One block per 16x16 output patch (blockIdx.x = s).
// ===========================================================================
__global__ __launch_bounds__(256) void k_resconv(
    const float* __restrict__ x, const float* __restrict__ rcw, const float* __restrict__ rcb,
    __hip_bfloat16* __restrict__ abf)
{
    __shared__ float xs[3][8][8];
    __shared__ float wsm[1728];       // [64][3][3][3]
    __shared__ float rs[3][18][18];   // resized halo tile
    int t = threadIdx.x;
    if (t < 192) xs[t / 64][(t / 8) % 8][t % 8] = x[t];
    for (int i = t; i < 1728; i += 256) wsm[i] = rcw[i];
    int py = blockIdx.x >> 6, px = blockIdx.x & 63;
    int Y0 = py * 16, X0 = px * 16;
    __syncthreads();
    for (int o = t; o < 972; o += 256) {
        int ic = o / 324, rr = (o / 18) % 18, cc = o % 18;
        int u = Y0 - 1 + rr, v = X0 - 1 + cc;
        float val = 0.0f;
        if (u >= 0 && u < 1024 && v >= 0 && v < 1024) {
            float fu = (u + 0.5f) * 0.0078125f - 0.5f;
            float fv = (v + 0.5f) * 0.0078125f - 0.5f;
            float fi = floorf(fu), fj = floorf(fv);
            float tu = fu - fi, tv = fv - fj;
            int i0 = (int)fi, j0 = (int)fj;
            int i0c = min(max(i0, 0), 7), i1c = min(max(i0 + 1, 0), 7);
            int j0c = min(max(j0, 0), 7), j1c = min(max(j0 + 1, 0), 7);
            float a00 = xs[ic][i0c][j0c], a01 = xs[ic][i0c][j1c];
            float a10 = xs[ic][i1c][j0c], a11 = xs[ic][i1c][j1c];
            val = (a00 * (1.f - tv) + a01 * tv) * (1.f - tu)
                + (a10 * (1.f - tv) + a11 * tv) * tu;
        }
        rs[ic][rr][cc] = val;
    }
    __syncthreads();
    int ly = t >> 4, lx = t & 15;
    float rv[3][3][3];
    #pragma unroll
    for (int ic = 0; ic < 3; ++ic)
        #pragma unroll
        for (int ky = 0; ky < 3; ++ky)
            #pragma unroll
            for (int kx = 0; kx < 3; ++kx)
                rv[ic][ky][kx] = rs[ic][ly + ky][lx + kx];
    size_t sbase = (size_t)blockIdx.x * 16384 + t;
    for (int c = 0; c < 64; ++c) {
        float acc = rcb[c];
        const float* wp = &wsm[c * 27];
        #pragma unroll
        for (int ic = 0; ic < 3; ++ic)
            #pragma unroll
            for (int ky = 0; ky < 3; ++ky)
                #pragma unroll
                for (int kx = 0; kx < 3; ++kx)
                    acc = fmaf(rv[ic][ky][kx], wp[ic * 9 + ky * 3 + kx], acc);
        abf[sbase + c * 256] = __float2bfloat16(acc);
    }
}

// ===========================================================================
// Cast f32 -> bf16, vectorized (n must be divisible by 1024).
// ===========================================================================
__global__ __launch_bounds__(256) void k_cast_bf16(
    const float* __restrict__ in, __hip_bfloat16* __restrict__ out, long n)
{
    long i = ((long)blockIdx.x * 256 + threadIdx.x) * 4;
    if (i >= n) return;
    float4 v = *(const float4*)(in + i);
    __hip_bfloat16 h[4] = {__float2bfloat16(v.x), __float2bfloat16(v.y),
                           __float2bfloat16(v.z), __float2bfloat16(v.w)};
    *(ushort4*)(out + i) = *(const ushort4*)h;
}

// ===========================================================================
// bf16 MFMA NT GEMM: C[m*N+n] = bias + sum_k A[m,k] * B[n,k]   (f32 accum)
// A: [M][K] bf16 row-major; B: [N][K] bf16 row-major. 128x128 tile, BK=64.
// 4 waves (2x2), each computes 64x64 via 4x4 mfma_f32_16x16x32_bf16 frags.
// LDS: linear dest for global_load_lds + inverse-swizzled global source +
// XOR-swizzled ds_read (byte ^= (row&7)<<4)  -> conflict-free b128 reads.
// BIASROW: 1 -> bias[m], 0 -> bias[n].
// ===========================================================================
template <int BIASROW>
__global__ __launch_bounds__(256) void gemm_bf16_nt(
    const __hip_bfloat16* __restrict__ A, const __hip_bfloat16* __restrict__ B,
    const float* __restrict__ bias, float* __restrict__ C,
    int M, int N, int K)
{
    constexpr int BK = 64;                   // k per LDS tile
    __shared__ short lds[2 * 128 * BK];      // As then Bs, each [128][64] bf16
    short* As = lds;
    short* Bs = lds + 128 * BK;
    const short* Ag = (const short*)A;
    const short* Bg = (const short*)B;
    int t = threadIdx.x;
    int wid = t >> 6, lane = t & 63;
    int m0 = blockIdx.y * 128, n0 = blockIdx.x * 128;
    int wr = wid >> 1, wc = wid & 1;         // wave's 64x64 sub-tile
    f32x4 acc[4][4] = {};                    // [mt][nt]

    // staging geometry: instr i of wave covers rows r0 = i*32 + wid*8 .. +7.
    // lane L writes LDS bytes [r0*128 + L*16 .. +16); the data that must land
    // there (so swizzled reads work) is logical chunk (L&7)^(r&7) of row r.
    int srow = lane >> 3;                    // 0..7 within 8-row group
    for (int k0 = 0; k0 < K; k0 += BK) {
        #pragma unroll
        for (int i = 0; i < 4; ++i) {
            int r0 = i * 32 + wid * 8;
            int r = r0 + srow;
            int chunk = (lane & 7) ^ (r & 7);
            GLOAD16(Ag + (size_t)(m0 + r) * K + k0 + chunk * 8, As + r0 * BK);
            GLOAD16(Bg + (size_t)(n0 + r) * K + k0 + chunk * 8, Bs + r0 * BK);
        }
        __syncthreads();
        #pragma unroll
        for (int ks = 0; ks < 2; ++ks) {
            bf16x8 af[4], bfr[4];
            #pragma unroll
            for (int mt = 0; mt < 4; ++mt) {
                int r = wr * 64 + mt * 16 + (lane & 15);
                int cb = ks * 64 + (lane >> 4) * 16;
                af[mt] = *(const bf16x8*)((const char*)As + r * 128 + (cb ^ ((r & 7) << 4)));
            }
            #pragma unroll
            for (int nt = 0; nt < 4; ++nt) {
                int r = wc * 64 + nt * 16 + (lane & 15);
                int cb = ks * 64 + (lane >> 4) * 16;
                bfr[nt] = *(const bf16x8*)((const char*)Bs + r * 128 + (cb ^ ((r & 7) << 4)));
            }
            #pragma unroll
            for (int mt = 0; mt < 4; ++mt)
                #pragma unroll
                for (int nt = 0; nt < 4; ++nt)
                    acc[mt][nt] = __builtin_amdgcn_mfma_f32_16x16x32_bf16(
                        af[mt], bfr[nt], acc[mt][nt], 0, 0, 0);
        }
        __syncthreads();
    }
    // epilogue: D lane layout col = lane&15, row = (lane>>4)*4 + reg
    #pragma unroll
    for (int mt = 0; mt < 4; ++mt) {
        #pragma unroll
        for (int nt = 0; nt < 4; ++nt) {
            int col = n0 + wc * 64 + nt * 16 + (lane & 15);
            #pragma unroll
            for (int rg = 0; rg < 4; ++rg) {
                int row = m0 + wr * 64 + mt * 16 + (lane >> 4) * 4 + rg;
                float bb = BIASROW ? bias[row] : bias[col];
                C[(size_t)row * N + col] = acc[mt][nt][rg] + bb;
            }
        }
    }
}

// ===========================================================================
// Kernel 4: fused q-chain + attn + out_win; updates P in place with residual.
// ===========================================================================
__global__ __launch_bounds__(256) void k_attn(
    float* __restrict__ P, const float* __restrict__ b_buf, const float* __restrict__ b_rot,
    const float* __restrict__ qpw, const float* __restrict__ qpb,
    const float* __restrict__ nqg, const float* __restrict__ nqb,
    const float* __restrict__ qaw, const float* __restrict__ qab,
    const float* __restrict__ pos, float* __restrict__ attn_out)
{
    __shared__ float bs[16][4], brs[16][4];
    int t = threadIdx.x;
    int wh = blockIdx.y;
    int wi = wh >> 4, h = wh & 15;
    if (t < 64) {
        ((float*)bs)[t]  = b_buf[wh * 64 + t];
        ((float*)brs)[t] = b_rot[wh * 64 + t];
    }
    __syncthreads();
    int p = blockIdx.x * 256 + t;
    int wr = p >> 8, wc = p & 255;
    int gr = ((wi >> 1) << 8) + wr, gc = ((wi & 1) << 8) + wc;
    int y = gr >> 3, hnr = gr & 7, xq = gc >> 3, wnr = gc & 7;
    size_t base = (size_t)(y * 64 + xq) * 4096 + h * 256 + hnr * 8 + wnr;
    float r[4];
    #pragma unroll
    for (int d = 0; d < 4; ++d) r[d] = P[base + (size_t)d * 64];
    float mu = 0.25f * (r[0] + r[1] + r[2] + r[3]);
    float var = 0.25f * ((r[0]-mu)*(r[0]-mu) + (r[1]-mu)*(r[1]-mu) +
                         (r[2]-mu)*(r[2]-mu) + (r[3]-mu)*(r[3]-mu));
    float inv = rsqrtf(var + 1e-5f);
    float xh[4];
    #pragma unroll
    for (int d = 0; d < 4; ++d) xh[d] = (r[d] - mu) * inv * nqg[d] + nqb[d];
    float q4[4];
    #pragma unroll
    for (int d = 0; d < 4; ++d) {
        float a = qpb[d];
        #pragma unroll
        for (int e = 0; e < 4; ++e) a = fmaf(xh[e], qpw[d * 4 + e], a);
        q4[d] = a;
    }
    float z = qab[0];
    #pragma unroll
    for (int d = 0; d < 4; ++d) z = fmaf(q4[d], qaw[d], z);
    float gate = 1.0f / (1.0f + expf(-z));
    float4 pv = *(const float4*)(pos + ((size_t)h * 65536 + p) * 4);
    float v[4];
    v[0] = q4[0] * gate + pv.x * (1.0f - gate);
    v[1] = q4[1] * gate + pv.y * (1.0f - gate);
    v[2] = q4[2] * gate + pv.z * (1.0f - gate);
    v[3] = q4[3] * gate + pv.w * (1.0f - gate);
    float nn = sqrtf(v[0]*v[0] + v[1]*v[1] + v[2]*v[2] + v[3]*v[3]);
    float in2 = 1.0f / fmaxf(nn, 1e-12f);
    #pragma unroll
    for (int d = 0; d < 4; ++d) v[d] *= in2;
    float s0, c0, s1, c1;
    sincosf((float)wr, &s0, &c0);
    sincosf((float)wc, &s1, &c1);
    float qr[4];
    qr[0] = v[0] * c0 - v[1] * s0;
    qr[1] = v[0] * s0 + v[1] * c0;
    qr[2] = v[2] * c1 - v[3] * s1;
    qr[3] = v[2] * s1 + v[3] * c1;
    float arow[16];
    #pragma unroll
    for (int k = 0; k < 16; ++k)
        arow[k] = qr[0] * brs[k][0] + qr[1] * brs[k][1] + qr[2] * brs[k][2] + qr[3] * brs[k][3];
    size_t abase = ((size_t)wh * 65536 + p) * 16;
    #pragma unroll
    for (int kq = 0; kq < 4; ++kq) {
        float4 av;
        av.x = arow[kq * 4 + 0]; av.y = arow[kq * 4 + 1];
        av.z = arow[kq * 4 + 2]; av.w = arow[kq * 4 + 3];
        *(float4*)(attn_out + abase + kq * 4) = av;
    }
    float o[4] = {0.f, 0.f, 0.f, 0.f};
    #pragma unroll
    for (int k = 0; k < 16; ++k) {
        #pragma unroll
        for (int d = 0; d < 4; ++d) o[d] = fmaf(arow[k], bs[k][d], o[d]);
    }
    #pragma unroll
    for (int d = 0; d < 4; ++d) P[base + (size_t)d * 64] = r[d] + o[d];
}

// ===========================================================================
extern "C" void kernel_launch(void* const* d_in, const int* in_sizes, int n_in,
                              void* d_out, int out_size, void* d_ws, size_t ws_size,
                              hipStream_t stream)
{
    (void)in_sizes; (void)n_in; (void)out_size; (void)ws_size;
    const float* x    = (const float*)d_in[0];
    const float* xcw  = (const float*)d_in[1];
    const float* xcb  = (const float*)d_in[2];
    const float* rcw  = (const float*)d_in[3];
    const float* rcb  = (const float*)d_in[4];
    const float* pw   = (const float*)d_in[5];
    const float* pb   = (const float*)d_in[6];
    const float* bpw  = (const float*)d_in[7];
    const float* bpb  = (const float*)d_in[8];
    const float* qpw  = (const float*)d_in[9];
    const float* qpb  = (const float*)d_in[10];
    const float* nbg  = (const float*)d_in[11];
    const float* nbb  = (const float*)d_in[12];
    const float* nqg  = (const float*)d_in[13];
    const float* nqb  = (const float*)d_in[14];
    const float* qaw  = (const float*)d_in[15];
    const float* qab  = (const float*)d_in[16];
    const float* pos  = (const float*)d_in[17];
    const float* prw  = (const float*)d_in[18];
    const float* prb  = (const float*)d_in[19];

    float* ws = (float*)d_ws;
    __hip_bfloat16* abf  = (__hip_bfloat16*)d_ws;                       // [4096][16384]
    __hip_bfloat16* pwb  = (__hip_bfloat16*)d_ws + 67108864ull;        // [4096][16384]
    float*          P    = ws + P_F;                                    // [4096][4096]
    float*          b_buf = ws + BBUF_F;
    float*          b_rot = ws + BROT_F;
    __hip_bfloat16* Pb   = (__hip_bfloat16*)d_ws;                       // reuse abf space
    __hip_bfloat16* prwb = (__hip_bfloat16*)d_ws + 67108864ull;        // reuse pwb space
    float* out = (float*)d_out;

    k_bchain<<<1, 256, 0, stream>>>(x, xcw, xcb, bpw, bpb, nbg, nbb, b_buf, b_rot);
    k_resconv<<<4096, 256, 0, stream>>>(x, rcw, rcb, abf);
    k_cast_bf16<<<65536, 256, 0, stream>>>(pw, pwb, 67108864L);
    // patch conv: M = s(4096), N = co(4096), K = 16384; C = P[s][co], bias per col
    gemm_bf16_nt<0><<<dim3(32, 32), 256, 0, stream>>>(abf, pwb, pb, P, 4096, 4096, 16384);
    // fused q-chain / attn / out_win (+ residual into P)
    k_attn<<<dim3(256, 64), 256, 0, stream>>>(P, b_buf, b_rot, qpw, qpb, nqg, nqb,
                                              qaw, qab, pos, out + ATTN_OFF);
    k_cast_bf16<<<16384, 256, 0, stream>>>(prw, prwb, 16777216L);
    k_cast_bf16<<<16384, 256, 0, stream>>>(P, Pb, 16777216L);
    // 1x1 proj: M = co(4096), N = s(4096), K = 4096; C = out[co][s], bias per row
    gemm_bf16_nt<1><<<dim3(32, 32), 256, 0, stream>>>(prwb, Pb, prb, out, 4096, 4096, 4096);
}

// Round 3
// 1269.341 us; speedup vs baseline: 6.8970x; 1.0154x over previous
//
#include <hip/hip_runtime.h>
#include <hip/hip_bf16.h>
#include <math.h>
#include <cstddef>

// ---------------------------------------------------------------------------
// Workspace layout. Peak 335.6 MB.
//   Abf  : bf16 [4096][16384]  patch-GEMM A operand     shorts [0 .. 67108864)
//   pwb  : bf16 [4096][16384]  patch_w cast             shorts [67108864 ..)
//   P    : f32  [4096 s][4096 co]                       floats [67108864 ..)
//   b_buf/b_rot : floats 83886080 / 83890176
//   After patch GEMM: Pb (reuse Abf), prwb (reuse pwb).
// ---------------------------------------------------------------------------
#define P_F      67108864ull
#define BBUF_F   83886080ull
#define BROT_F   83890176ull
#define ATTN_OFF 16777216ull

typedef __attribute__((ext_vector_type(8))) short bf16x8;
typedef __attribute__((ext_vector_type(4))) float f32x4;

#define GLOAD16(gsrc, ldst) \
  __builtin_amdgcn_global_load_lds((const __attribute__((address_space(1))) void*)(gsrc), \
                                   (__attribute__((address_space(3))) void*)(ldst), 16, 0, 0)

// ===========================================================================
// Kernel 1: x_feat conv + b-chain (LN, proj, l2, rope)
// ===========================================================================
__global__ __launch_bounds__(256) void k_bchain(
    const float* __restrict__ x, const float* __restrict__ xcw, const float* __restrict__ xcb,
    const float* __restrict__ bpw, const float* __restrict__ bpb,
    const float* __restrict__ nbg, const float* __restrict__ nbb,
    float* __restrict__ b_buf, float* __restrict__ b_rot)
{
    __shared__ float xs[3][8][8];
    __shared__ float xf[64][8][8];
    int t = threadIdx.x;
    if (t < 192) xs[t / 64][(t / 8) % 8][t % 8] = x[t];
    __syncthreads();
    for (int o = t; o < 4096; o += 256) {
        int c = o >> 6, i = (o >> 3) & 7, j = o & 7;
        float acc = xcb[c];
        for (int ic = 0; ic < 3; ++ic)
            for (int ky = 0; ky < 3; ++ky)
                for (int kx = 0; kx < 3; ++kx) {
                    int ii = i - 1 + ky, jj = j - 1 + kx;
                    if (ii >= 0 && ii < 8 && jj >= 0 && jj < 8)
                        acc = fmaf(xs[ic][ii][jj], xcw[((c * 3 + ic) * 3 + ky) * 3 + kx], acc);
                }
        xf[c][i][j] = acc;
    }
    __syncthreads();
    for (int idx = t; idx < 1024; idx += 256) {
        int wi = idx >> 8, h = (idx >> 4) & 15, pp = idx & 15;
        int pr = pp >> 2, pc = pp & 3;
        int gi = 4 * (wi >> 1) + pr, gj = 4 * (wi & 1) + pc;
        float v[4];
        #pragma unroll
        for (int d = 0; d < 4; ++d) v[d] = xf[h * 4 + d][gi][gj];
        float mu = 0.25f * (v[0] + v[1] + v[2] + v[3]);
        float var = 0.25f * ((v[0]-mu)*(v[0]-mu) + (v[1]-mu)*(v[1]-mu) +
                             (v[2]-mu)*(v[2]-mu) + (v[3]-mu)*(v[3]-mu));
        float inv = rsqrtf(var + 1e-5f);
        float xh[4];
        #pragma unroll
        for (int d = 0; d < 4; ++d) xh[d] = (v[d] - mu) * inv * nbg[d] + nbb[d];
        float bv[4];
        #pragma unroll
        for (int d = 0; d < 4; ++d) {
            float a = bpb[d];
            #pragma unroll
            for (int e = 0; e < 4; ++e) a = fmaf(xh[e], bpw[d * 4 + e], a);
            bv[d] = a;
        }
        #pragma unroll
        for (int d = 0; d < 4; ++d) b_buf[idx * 4 + d] = bv[d];
        float nn = sqrtf(bv[0]*bv[0] + bv[1]*bv[1] + bv[2]*bv[2] + bv[3]*bv[3]);
        float in2 = 1.0f / fmaxf(nn, 1e-12f);
        float bn[4];
        #pragma unroll
        for (int d = 0; d < 4; ++d) bn[d] = bv[d] * in2;
        float s0, c0, s1, c1;
        sincosf((float)pr, &s0, &c0);
        sincosf((float)pc, &s1, &c1);
        b_rot[idx * 4 + 0] = bn[0] * c0 - bn[1] * s0;
        b_rot[idx * 4 + 1] = bn[0] * s0 + bn[1] * c0;
        b_rot[idx * 4 + 2] = bn[2] * c1 - bn[3] * s1;
        b_rot[idx * 4 + 3] = bn[2] * s1 + bn[3] * c1;
    }
}

// ===========================================================================
// Kernel 2: fused bilinear resize + 3x3 conv -> bf16 A operand [s][16384]
// ===========================================================================
__global__ __launch_bounds__(256) void k_resconv(
    const float* __restrict__ x, const float* __restrict__ rcw, const float* __restrict__ rcb,
    __hip_bfloat16* __restrict__ abf)
{
    __shared__ float xs[3][8][8];
    __shared__ float wsm[1728];
    __shared__ float rs[3][18][18];
    int t = threadIdx.x;
    if (t < 192) xs[t / 64][(t / 8) % 8][t % 8] = x[t];
    for (int i = t; i < 1728; i += 256) wsm[i] = rcw[i];
    int py = blockIdx.x >> 6, px = blockIdx.x & 63;
    int Y0 = py * 16, X0 = px * 16;
    __syncthreads();
    for (int o = t; o < 972; o += 256) {
        int ic = o / 324, rr = (o / 18) % 18, cc = o % 18;
        int u = Y0 - 1 + rr, v = X0 - 1 + cc;
        float val = 0.0f;
        if (u >= 0 && u < 1024 && v >= 0 && v < 1024) {
            float fu = (u + 0.5f) * 0.0078125f - 0.5f;
            float fv = (v + 0.5f) * 0.0078125f - 0.5f;
            float fi = floorf(fu), fj = floorf(fv);
            float tu = fu - fi, tv = fv - fj;
            int i0 = (int)fi, j0 = (int)fj;
            int i0c = min(max(i0, 0), 7), i1c = min(max(i0 + 1, 0), 7);
            int j0c = min(max(j0, 0), 7), j1c = min(max(j0 + 1, 0), 7);
            float a00 = xs[ic][i0c][j0c], a01 = xs[ic][i0c][j1c];
            float a10 = xs[ic][i1c][j0c], a11 = xs[ic][i1c][j1c];
            val = (a00 * (1.f - tv) + a01 * tv) * (1.f - tu)
                + (a10 * (1.f - tv) + a11 * tv) * tu;
        }
        rs[ic][rr][cc] = val;
    }
    __syncthreads();
    int ly = t >> 4, lx = t & 15;
    float rv[3][3][3];
    #pragma unroll
    for (int ic = 0; ic < 3; ++ic)
        #pragma unroll
        for (int ky = 0; ky < 3; ++ky)
            #pragma unroll
            for (int kx = 0; kx < 3; ++kx)
                rv[ic][ky][kx] = rs[ic][ly + ky][lx + kx];
    size_t sbase = (size_t)blockIdx.x * 16384 + t;
    for (int c = 0; c < 64; ++c) {
        float acc = rcb[c];
        const float* wp = &wsm[c * 27];
        #pragma unroll
        for (int ic = 0; ic < 3; ++ic)
            #pragma unroll
            for (int ky = 0; ky < 3; ++ky)
                #pragma unroll
                for (int kx = 0; kx < 3; ++kx)
                    acc = fmaf(rv[ic][ky][kx], wp[ic * 9 + ky * 3 + kx], acc);
        abf[sbase + c * 256] = __float2bfloat16(acc);
    }
}

// ===========================================================================
__global__ __launch_bounds__(256) void k_cast_bf16(
    const float* __restrict__ in, __hip_bfloat16* __restrict__ out, long n)
{
    long i = ((long)blockIdx.x * 256 + threadIdx.x) * 4;
    if (i >= n) return;
    float4 v = *(const float4*)(in + i);
    __hip_bfloat16 h[4] = {__float2bfloat16(v.x), __float2bfloat16(v.y),
                           __float2bfloat16(v.z), __float2bfloat16(v.w)};
    *(ushort4*)(out + i) = *(const ushort4*)h;
}

// ===========================================================================
// Deep-pipelined bf16 MFMA NT GEMM.  C[m*N+n] = bias + sum_k A[m,k]*B[n,k]
// BM=256, BN=128, BK=64. 512 threads = 8 waves (4M x 2N), wave tile 64x64.
// 3 LDS buffers (48 KB each), prefetch distance 2, counted vmcnt(6) at tile
// top (never drains in main loop), raw s_barrier, 2 phases/tile with
// setprio(1) around the 16-MFMA cluster. T2 XOR swizzle on both sides.
// ===========================================================================
template <int BIASROW>
__global__ __launch_bounds__(512) void gemm_pipe(
    const __hip_bfloat16* __restrict__ A, const __hip_bfloat16* __restrict__ B,
    const float* __restrict__ bias, float* __restrict__ C,
    int M, int N, int K)
{
    __shared__ short lds[73728];               // 3 x (As 16384 + Bs 8192) shorts
    const short* Ag = (const short*)A;
    const short* Bg = (const short*)B;
    int t = threadIdx.x;
    int lane = t & 63;
    int wid = t >> 6;
    int wm = wid >> 1, wn = wid & 1;           // 4M x 2N wave grid

    // XCD-aware block swizzle (nwg % 8 == 0 for all our launches)
    int nwg = gridDim.x * gridDim.y;
    int flat = blockIdx.y * gridDim.x + blockIdx.x;
    int swz = (flat & 7) * (nwg >> 3) + (flat >> 3);
    int bx = swz % gridDim.x, by = swz / gridDim.x;
    int m0 = by * 256, n0 = bx * 128;
    int T = K >> 6;

    // staging geometry: 6 gload_lds per thread per K-tile.
    // piece 0,1 = B rows [p*64..), piece 2..5 = A rows [(p-2)*64..).
    // thread t covers row (piece_base + (t>>3)), source chunk (t&7)^(row&7).
    int srow = t >> 3;                          // 0..63 within piece
    int sc = ((t & 7) ^ (srow & 7)) * 8;        // element offset in K-tile
    const short* Asrc[4];
    const short* Bsrc[2];
    #pragma unroll
    for (int i = 0; i < 4; ++i)
        Asrc[i] = Ag + (size_t)(m0 + i * 64 + srow) * K + sc;
    #pragma unroll
    for (int j = 0; j < 2; ++j)
        Bsrc[j] = Bg + (size_t)(n0 + j * 64 + srow) * K + sc;
    // LDS dest (shorts): As piece i -> buf + i*4096 + t*8 ; Bs piece j -> buf+16384+j*4096+t*8

    f32x4 acc[4][4] = {};

    // prologue: issue tiles 0 and 1 (12 loads/thread in flight)
    #pragma unroll
    for (int u = 0; u < 2; ++u) {
        int bb = u * 24576;
        size_t koff = (size_t)u * 64;
        GLOAD16(Bsrc[0] + koff, lds + bb + 16384 + t * 8);
        GLOAD16(Bsrc[1] + koff, lds + bb + 20480 + t * 8);
        GLOAD16(Asrc[0] + koff, lds + bb +         t * 8);
        GLOAD16(Asrc[1] + koff, lds + bb +  4096 + t * 8);
        GLOAD16(Asrc[2] + koff, lds + bb +  8192 + t * 8);
        GLOAD16(Asrc[3] + koff, lds + bb + 12288 + t * 8);
    }

    for (int tt = 0; tt < T; ++tt) {
        // certify tile tt landed: retire its 6 loads, keep tile tt+1's 6 in flight
        if (tt + 1 < T) { asm volatile("s_waitcnt vmcnt(6)" ::: "memory"); }
        else           { asm volatile("s_waitcnt vmcnt(0)" ::: "memory"); }
        __builtin_amdgcn_s_barrier();
        __builtin_amdgcn_sched_barrier(0);

        const short* As = lds + (tt % 3) * 24576;
        const short* Bs = As + 16384;
        int pb = ((tt + 2) % 3) * 24576;
        bool pf = (tt + 2) < T;
        size_t koff = (size_t)(tt + 2) * 64;

        bf16x8 bfr[4][2];
        #pragma unroll
        for (int p = 0; p < 2; ++p) {
            // ds-read this phase's A quadrant (m-frags 2p, 2p+1)
            bf16x8 af[2][2];
            #pragma unroll
            for (int mh = 0; mh < 2; ++mh) {
                int rA = wm * 64 + (2 * p + mh) * 16 + (lane & 15);
                #pragma unroll
                for (int ks = 0; ks < 2; ++ks) {
                    int cb = ks * 64 + (lane >> 4) * 16;
                    af[mh][ks] = *(const bf16x8*)((const char*)As + rA * 128 + (cb ^ ((rA & 7) << 4)));
                }
            }
            if (p == 0) {
                #pragma unroll
                for (int nt = 0; nt < 4; ++nt) {
                    int rB = wn * 64 + nt * 16 + (lane & 15);
                    #pragma unroll
                    for (int ks = 0; ks < 2; ++ks) {
                        int cb = ks * 64 + (lane >> 4) * 16;
                        bfr[nt][ks] = *(const bf16x8*)((const char*)Bs + rB * 128 + (cb ^ ((rB & 7) << 4)));
                    }
                }
            }
            // issue prefetch for tile tt+2 (3 pieces per phase)
            if (pf) {
                if (p == 0) {
                    GLOAD16(Bsrc[0] + koff, lds + pb + 16384 + t * 8);
                    GLOAD16(Bsrc[1] + koff, lds + pb + 20480 + t * 8);
                    GLOAD16(Asrc[0] + koff, lds + pb +         t * 8);
                } else {
                    GLOAD16(Asrc[1] + koff, lds + pb +  4096 + t * 8);
                    GLOAD16(Asrc[2] + koff, lds + pb +  8192 + t * 8);
                    GLOAD16(Asrc[3] + koff, lds + pb + 12288 + t * 8);
                }
            }
            __builtin_amdgcn_s_barrier();
            __builtin_amdgcn_s_setprio(1);
            #pragma unroll
            for (int mh = 0; mh < 2; ++mh)
                #pragma unroll
                for (int nt = 0; nt < 4; ++nt)
                    #pragma unroll
                    for (int ks = 0; ks < 2; ++ks)
                        acc[2 * p + mh][nt] = __builtin_amdgcn_mfma_f32_16x16x32_bf16(
                            af[mh][ks], bfr[nt][ks], acc[2 * p + mh][nt], 0, 0, 0);
            __builtin_amdgcn_s_setprio(0);
            __builtin_amdgcn_s_barrier();
        }
    }

    // epilogue: D layout col = lane&15, row = (lane>>4)*4 + reg
    #pragma unroll
    for (int mt = 0; mt < 4; ++mt) {
        #pragma unroll
        for (int nt = 0; nt < 4; ++nt) {
            int col = n0 + wn * 64 + nt * 16 + (lane & 15);
            #pragma unroll
            for (int rg = 0; rg < 4; ++rg) {
                int row = m0 + wm * 64 + mt * 16 + (lane >> 4) * 4 + rg;
                float bb = BIASROW ? bias[row] : bias[col];
                C[(size_t)row * N + col] = acc[mt][nt][rg] + bb;
            }
        }
    }
}

// ===========================================================================
// Kernel 4: fused q-chain + attn + out_win; updates P in place with residual.
// ===========================================================================
__global__ __launch_bounds__(256) void k_attn(
    float* __restrict__ P, const float* __restrict__ b_buf, const float* __restrict__ b_rot,
    const float* __restrict__ qpw, const float* __restrict__ qpb,
    const float* __restrict__ nqg, const float* __restrict__ nqb,
    const float* __restrict__ qaw, const float* __restrict__ qab,
    const float* __restrict__ pos, float* __restrict__ attn_out)
{
    __shared__ float bs[16][4], brs[16][4];
    int t = threadIdx.x;
    int wh = blockIdx.y;
    int wi = wh >> 4, h = wh & 15;
    if (t < 64) {
        ((float*)bs)[t]  = b_buf[wh * 64 + t];
        ((float*)brs)[t] = b_rot[wh * 64 + t];
    }
    __syncthreads();
    int p = blockIdx.x * 256 + t;
    int wr = p >> 8, wc = p & 255;
    int gr = ((wi >> 1) << 8) + wr, gc = ((wi & 1) << 8) + wc;
    int y = gr >> 3, hnr = gr & 7, xq = gc >> 3, wnr = gc & 7;
    size_t base = (size_t)(y * 64 + xq) * 4096 + h * 256 + hnr * 8 + wnr;
    float r[4];
    #pragma unroll
    for (int d = 0; d < 4; ++d) r[d] = P[base + (size_t)d * 64];
    float mu = 0.25f * (r[0] + r[1] + r[2] + r[3]);
    float var = 0.25f * ((r[0]-mu)*(r[0]-mu) + (r[1]-mu)*(r[1]-mu) +
                         (r[2]-mu)*(r[2]-mu) + (r[3]-mu)*(r[3]-mu));
    float inv = rsqrtf(var + 1e-5f);
    float xh[4];
    #pragma unroll
    for (int d = 0; d < 4; ++d) xh[d] = (r[d] - mu) * inv * nqg[d] + nqb[d];
    float q4[4];
    #pragma unroll
    for (int d = 0; d < 4; ++d) {
        float a = qpb[d];
        #pragma unroll
        for (int e = 0; e < 4; ++e) a = fmaf(xh[e], qpw[d * 4 + e], a);
        q4[d] = a;
    }
    float z = qab[0];
    #pragma unroll
    for (int d = 0; d < 4; ++d) z = fmaf(q4[d], qaw[d], z);
    float gate = 1.0f / (1.0f + expf(-z));
    float4 pv = *(const float4*)(pos + ((size_t)h * 65536 + p) * 4);
    float v[4];
    v[0] = q4[0] * gate + pv.x * (1.0f - gate);
    v[1] = q4[1] * gate + pv.y * (1.0f - gate);
    v[2] = q4[2] * gate + pv.z * (1.0f - gate);
    v[3] = q4[3] * gate + pv.w * (1.0f - gate);
    float nn = sqrtf(v[0]*v[0] + v[1]*v[1] + v[2]*v[2] + v[3]*v[3]);
    float in2 = 1.0f / fmaxf(nn, 1e-12f);
    #pragma unroll
    for (int d = 0; d < 4; ++d) v[d] *= in2;
    float s0, c0, s1, c1;
    sincosf((float)wr, &s0, &c0);
    sincosf((float)wc, &s1, &c1);
    float qr[4];
    qr[0] = v[0] * c0 - v[1] * s0;
    qr[1] = v[0] * s0 + v[1] * c0;
    qr[2] = v[2] * c1 - v[3] * s1;
    qr[3] = v[2] * s1 + v[3] * c1;
    float arow[16];
    #pragma unroll
    for (int k = 0; k < 16; ++k)
        arow[k] = qr[0] * brs[k][0] + qr[1] * brs[k][1] + qr[2] * brs[k][2] + qr[3] * brs[k][3];
    size_t abase = ((size_t)wh * 65536 + p) * 16;
    #pragma unroll
    for (int kq = 0; kq < 4; ++kq) {
        float4 av;
        av.x = arow[kq * 4 + 0]; av.y = arow[kq * 4 + 1];
        av.z = arow[kq * 4 + 2]; av.w = arow[kq * 4 + 3];
        *(float4*)(attn_out + abase + kq * 4) = av;
    }
    float o[4] = {0.f, 0.f, 0.f, 0.f};
    #pragma unroll
    for (int k = 0; k < 16; ++k) {
        #pragma unroll
        for (int d = 0; d < 4; ++d) o[d] = fmaf(arow[k], bs[k][d], o[d]);
    }
    #pragma unroll
    for (int d = 0; d < 4; ++d) P[base + (size_t)d * 64] = r[d] + o[d];
}

// ===========================================================================
extern "C" void kernel_launch(void* const* d_in, const int* in_sizes, int n_in,
                              void* d_out, int out_size, void* d_ws, size_t ws_size,
                              hipStream_t stream)
{
    (void)in_sizes; (void)n_in; (void)out_size; (void)ws_size;
    const float* x    = (const float*)d_in[0];
    const float* xcw  = (const float*)d_in[1];
    const float* xcb  = (const float*)d_in[2];
    const float* rcw  = (const float*)d_in[3];
    const float* rcb  = (const float*)d_in[4];
    const float* pw   = (const float*)d_in[5];
    const float* pb   = (const float*)d_in[6];
    const float* bpw  = (const float*)d_in[7];
    const float* bpb  = (const float*)d_in[8];
    const float* qpw  = (const float*)d_in[9];
    const float* qpb  = (const float*)d_in[10];
    const float* nbg  = (const float*)d_in[11];
    const float* nbb  = (const float*)d_in[12];
    const float* nqg  = (const float*)d_in[13];
    const float* nqb  = (const float*)d_in[14];
    const float* qaw  = (const float*)d_in[15];
    const float* qab  = (const float*)d_in[16];
    const float* pos  = (const float*)d_in[17];
    const float* prw  = (const float*)d_in[18];
    const float* prb  = (const float*)d_in[19];

    float* ws = (float*)d_ws;
    __hip_bfloat16* abf  = (__hip_bfloat16*)d_ws;
    __hip_bfloat16* pwb  = (__hip_bfloat16*)d_ws + 67108864ull;
    float*          P    = ws + P_F;
    float*          b_buf = ws + BBUF_F;
    float*          b_rot = ws + BROT_F;
    __hip_bfloat16* Pb   = (__hip_bfloat16*)d_ws;
    __hip_bfloat16* prwb = (__hip_bfloat16*)d_ws + 67108864ull;
    float* out = (float*)d_out;

    k_bchain<<<1, 256, 0, stream>>>(x, xcw, xcb, bpw, bpb, nbg, nbb, b_buf, b_rot);
    k_resconv<<<4096, 256, 0, stream>>>(x, rcw, rcb, abf);
    k_cast_bf16<<<65536, 256, 0, stream>>>(pw, pwb, 67108864L);
    // patch conv: M = s(4096), N = co(4096), K = 16384; C = P[s][co], bias per col
    gemm_pipe<0><<<dim3(32, 16), 512, 0, stream>>>(abf, pwb, pb, P, 4096, 4096, 16384);
    // fused q-chain / attn / out_win (+ residual into P)
    k_attn<<<dim3(256, 64), 256, 0, stream>>>(P, b_buf, b_rot, qpw, qpb, nqg, nqb,
                                              qaw, qab, pos, out + ATTN_OFF);
    k_cast_bf16<<<16384, 256, 0, stream>>>(prw, prwb, 16777216L);
    k_cast_bf16<<<16384, 256, 0, stream>>>(P, Pb, 16777216L);
    // 1x1 proj: M = co(4096), N = s(4096), K = 4096; C = out[co][s], bias per row
    gemm_pipe<1><<<dim3(32, 16), 512, 0, stream>>>(prwb, Pb, prb, out, 4096, 4096, 4096);
}

// Round 4
// 932.851 us; speedup vs baseline: 9.3849x; 1.3607x over previous
//
#include <hip/hip_runtime.h>
#include <hip/hip_bf16.h>
#include <math.h>
#include <cstddef>

// ---------------------------------------------------------------------------
// Workspace layout. Peak 335.6 MB.
//   Abf  : bf16 [4096][16384]  patch-GEMM A operand     shorts [0 .. 67108864)
//   pwb  : bf16 [4096][16384]  patch_w cast             shorts [67108864 ..)
//   P    : f32  [4096 s][4096 co]                       floats [67108864 ..)
//   b_buf/b_rot : floats 83886080 / 83890176
//   After patch GEMM: Pb (reuse Abf region), prwb (reuse pwb region).
// ---------------------------------------------------------------------------
#define P_F      67108864ull
#define BBUF_F   83886080ull
#define BROT_F   83890176ull
#define ATTN_OFF 16777216ull

typedef __attribute__((ext_vector_type(8))) short bf16x8;
typedef __attribute__((ext_vector_type(4))) float f32x4;

#define GLOAD16(gsrc, ldst) \
  __builtin_amdgcn_global_load_lds((const __attribute__((address_space(1))) void*)(gsrc), \
                                   (__attribute__((address_space(3))) void*)(ldst), 16, 0, 0)

// ===========================================================================
// Kernel 1: x_feat conv + b-chain (LN, proj, l2, rope)
// ===========================================================================
__global__ __launch_bounds__(256) void k_bchain(
    const float* __restrict__ x, const float* __restrict__ xcw, const float* __restrict__ xcb,
    const float* __restrict__ bpw, const float* __restrict__ bpb,
    const float* __restrict__ nbg, const float* __restrict__ nbb,
    float* __restrict__ b_buf, float* __restrict__ b_rot)
{
    __shared__ float xs[3][8][8];
    __shared__ float xf[64][8][8];
    int t = threadIdx.x;
    if (t < 192) xs[t / 64][(t / 8) % 8][t % 8] = x[t];
    __syncthreads();
    for (int o = t; o < 4096; o += 256) {
        int c = o >> 6, i = (o >> 3) & 7, j = o & 7;
        float acc = xcb[c];
        for (int ic = 0; ic < 3; ++ic)
            for (int ky = 0; ky < 3; ++ky)
                for (int kx = 0; kx < 3; ++kx) {
                    int ii = i - 1 + ky, jj = j - 1 + kx;
                    if (ii >= 0 && ii < 8 && jj >= 0 && jj < 8)
                        acc = fmaf(xs[ic][ii][jj], xcw[((c * 3 + ic) * 3 + ky) * 3 + kx], acc);
                }
        xf[c][i][j] = acc;
    }
    __syncthreads();
    for (int idx = t; idx < 1024; idx += 256) {
        int wi = idx >> 8, h = (idx >> 4) & 15, pp = idx & 15;
        int pr = pp >> 2, pc = pp & 3;
        int gi = 4 * (wi >> 1) + pr, gj = 4 * (wi & 1) + pc;
        float v[4];
        #pragma unroll
        for (int d = 0; d < 4; ++d) v[d] = xf[h * 4 + d][gi][gj];
        float mu = 0.25f * (v[0] + v[1] + v[2] + v[3]);
        float var = 0.25f * ((v[0]-mu)*(v[0]-mu) + (v[1]-mu)*(v[1]-mu) +
                             (v[2]-mu)*(v[2]-mu) + (v[3]-mu)*(v[3]-mu));
        float inv = rsqrtf(var + 1e-5f);
        float xh[4];
        #pragma unroll
        for (int d = 0; d < 4; ++d) xh[d] = (v[d] - mu) * inv * nbg[d] + nbb[d];
        float bv[4];
        #pragma unroll
        for (int d = 0; d < 4; ++d) {
            float a = bpb[d];
            #pragma unroll
            for (int e = 0; e < 4; ++e) a = fmaf(xh[e], bpw[d * 4 + e], a);
            bv[d] = a;
        }
        #pragma unroll
        for (int d = 0; d < 4; ++d) b_buf[idx * 4 + d] = bv[d];
        float nn = sqrtf(bv[0]*bv[0] + bv[1]*bv[1] + bv[2]*bv[2] + bv[3]*bv[3]);
        float in2 = 1.0f / fmaxf(nn, 1e-12f);
        float bn[4];
        #pragma unroll
        for (int d = 0; d < 4; ++d) bn[d] = bv[d] * in2;
        float s0, c0, s1, c1;
        sincosf((float)pr, &s0, &c0);
        sincosf((float)pc, &s1, &c1);
        b_rot[idx * 4 + 0] = bn[0] * c0 - bn[1] * s0;
        b_rot[idx * 4 + 1] = bn[0] * s0 + bn[1] * c0;
        b_rot[idx * 4 + 2] = bn[2] * c1 - bn[3] * s1;
        b_rot[idx * 4 + 3] = bn[2] * s1 + bn[3] * c1;
    }
}

// ===========================================================================
// Kernel 2: fused bilinear resize + 3x3 conv -> bf16 A operand [s][16384]
// ===========================================================================
__global__ __launch_bounds__(256) void k_resconv(
    const float* __restrict__ x, const float* __restrict__ rcw, const float* __restrict__ rcb,
    __hip_bfloat16* __restrict__ abf)
{
    __shared__ float xs[3][8][8];
    __shared__ float wsm[1728];
    __shared__ float rs[3][18][18];
    int t = threadIdx.x;
    if (t < 192) xs[t / 64][(t / 8) % 8][t % 8] = x[t];
    for (int i = t; i < 1728; i += 256) wsm[i] = rcw[i];
    int py = blockIdx.x >> 6, px = blockIdx.x & 63;
    int Y0 = py * 16, X0 = px * 16;
    __syncthreads();
    for (int o = t; o < 972; o += 256) {
        int ic = o / 324, rr = (o / 18) % 18, cc = o % 18;
        int u = Y0 - 1 + rr, v = X0 - 1 + cc;
        float val = 0.0f;
        if (u >= 0 && u < 1024 && v >= 0 && v < 1024) {
            float fu = (u + 0.5f) * 0.0078125f - 0.5f;
            float fv = (v + 0.5f) * 0.0078125f - 0.5f;
            float fi = floorf(fu), fj = floorf(fv);
            float tu = fu - fi, tv = fv - fj;
            int i0 = (int)fi, j0 = (int)fj;
            int i0c = min(max(i0, 0), 7), i1c = min(max(i0 + 1, 0), 7);
            int j0c = min(max(j0, 0), 7), j1c = min(max(j0 + 1, 0), 7);
            float a00 = xs[ic][i0c][j0c], a01 = xs[ic][i0c][j1c];
            float a10 = xs[ic][i1c][j0c], a11 = xs[ic][i1c][j1c];
            val = (a00 * (1.f - tv) + a01 * tv) * (1.f - tu)
                + (a10 * (1.f - tv) + a11 * tv) * tu;
        }
        rs[ic][rr][cc] = val;
    }
    __syncthreads();
    int ly = t >> 4, lx = t & 15;
    float rv[3][3][3];
    #pragma unroll
    for (int ic = 0; ic < 3; ++ic)
        #pragma unroll
        for (int ky = 0; ky < 3; ++ky)
            #pragma unroll
            for (int kx = 0; kx < 3; ++kx)
                rv[ic][ky][kx] = rs[ic][ly + ky][lx + kx];
    size_t sbase = (size_t)blockIdx.x * 16384 + t;
    for (int c = 0; c < 64; ++c) {
        float acc = rcb[c];
        const float* wp = &wsm[c * 27];
        #pragma unroll
        for (int ic = 0; ic < 3; ++ic)
            #pragma unroll
            for (int ky = 0; ky < 3; ++ky)
                #pragma unroll
                for (int kx = 0; kx < 3; ++kx)
                    acc = fmaf(rv[ic][ky][kx], wp[ic * 9 + ky * 3 + kx], acc);
        abf[sbase + c * 256] = __float2bfloat16(acc);
    }
}

// ===========================================================================
__global__ __launch_bounds__(256) void k_cast_bf16(
    const float* __restrict__ in, __hip_bfloat16* __restrict__ out, long n)
{
    long i = ((long)blockIdx.x * 256 + threadIdx.x) * 4;
    if (i >= n) return;
    float4 v = *(const float4*)(in + i);
    __hip_bfloat16 h[4] = {__float2bfloat16(v.x), __float2bfloat16(v.y),
                           __float2bfloat16(v.z), __float2bfloat16(v.w)};
    *(ushort4*)(out + i) = *(const ushort4*)h;
}

// ===========================================================================
// 8-phase-style bf16 MFMA NT GEMM (m201 geometry).
// C[m*N+n] = bias + sum_k A[m,k]*B[n,k]
// BM=BN=256, BK=64. 512 threads = 8 waves (2M x 4N), wave tile 128x64.
// LDS 128KB: 2 dbuf x (As[256][64] + Bs[256][64]) bf16.
// Per K-tile: 4 phases x 16 MFMA (one 64x32 C-quadrant each); every LDS word
// read once/K-tile via register fragment caching. Staging for tile tt+2 goes
// into the CURRENT buffer during ph2 (B) / ph3 (A), after its reads complete.
// vmcnt(8) at tile top only (8 loads/thread/tile in flight). T2 swizzle.
// ===========================================================================
template <int BIASROW>
__global__ __launch_bounds__(512) void gemm_8p(
    const __hip_bfloat16* __restrict__ A, const __hip_bfloat16* __restrict__ B,
    const float* __restrict__ bias, float* __restrict__ C,
    int M, int N, int K)
{
    __shared__ short lds[65536];                 // 128 KB
    const short* Ag = (const short*)A;
    const short* Bg = (const short*)B;
    int t = threadIdx.x;
    int lane = t & 63;
    int wid = t >> 6;
    int wm = wid >> 2, wn = wid & 3;             // 2M x 4N wave grid

    int nwg = gridDim.x * gridDim.y;
    int flat = blockIdx.y * gridDim.x + blockIdx.x;
    int swz = (flat & 7) * (nwg >> 3) + (flat >> 3);
    int bx = swz % gridDim.x, by = swz / gridDim.x;
    int m0 = by * 256, n0 = bx * 256;
    int T = K >> 6;

    // staging: per tile, 8 gloads/thread (A pieces 0-3, B pieces 0-3).
    // piece p covers rows p*64 + (t>>3); source chunk (t&7)^(row&7).
    int srow = t >> 3;
    int sc = ((t & 7) ^ (srow & 7)) * 8;
    const short* Asrc[4]; const short* Bsrc[4];
    #pragma unroll
    for (int p = 0; p < 4; ++p) {
        Asrc[p] = Ag + (size_t)(m0 + p * 64 + srow) * K + sc;
        Bsrc[p] = Bg + (size_t)(n0 + p * 64 + srow) * K + sc;
    }

    f32x4 acc[8][4] = {};

    // prologue: stage tile 0 -> buf0, tile 1 -> buf1 (16 loads in flight)
    #pragma unroll
    for (int u = 0; u < 2; ++u) {
        short* bA = lds + u * 32768;
        short* bB = bA + 16384;
        size_t ko = (size_t)u * 64;
        #pragma unroll
        for (int p = 0; p < 4; ++p) GLOAD16(Asrc[p] + ko, bA + p * 4096 + t * 8);
        #pragma unroll
        for (int p = 0; p < 4; ++p) GLOAD16(Bsrc[p] + ko, bB + p * 4096 + t * 8);
    }

    for (int tt = 0; tt < T; ++tt) {
        // certify tile tt's 8 loads; keep tile tt+1's 8 in flight
        if (tt + 1 < T) { asm volatile("s_waitcnt vmcnt(8)" ::: "memory"); }
        else            { asm volatile("s_waitcnt vmcnt(0)" ::: "memory"); }
        __builtin_amdgcn_s_barrier();
        __builtin_amdgcn_sched_barrier(0);

        const char* Asb = (const char*)(lds + (tt & 1) * 32768);
        const char* Bsb = Asb + 32768;           // +16384 shorts
        short* pA = lds + (tt & 1) * 32768;
        short* pB = pA + 16384;
        bool pf = (tt + 2) < T;
        size_t ko = (size_t)(tt + 2) * 64;

        bf16x8 af[4][2], bfr[4][2];
        // ---------------- ph0: read A-half0 (8) + B-half0 (4); MFMA Q(m0,n0)
        #pragma unroll
        for (int f = 0; f < 4; ++f) {
            int r = wm * 128 + f * 16 + (lane & 15);
            #pragma unroll
            for (int ks = 0; ks < 2; ++ks) {
                int cb = ks * 64 + (lane >> 4) * 16;
                af[f][ks] = *(const bf16x8*)(Asb + r * 128 + (cb ^ ((r & 7) << 4)));
            }
        }
        #pragma unroll
        for (int g = 0; g < 2; ++g) {
            int r = wn * 64 + g * 16 + (lane & 15);
            #pragma unroll
            for (int ks = 0; ks < 2; ++ks) {
                int cb = ks * 64 + (lane >> 4) * 16;
                bfr[g][ks] = *(const bf16x8*)(Bsb + r * 128 + (cb ^ ((r & 7) << 4)));
            }
        }
        __builtin_amdgcn_s_barrier();
        __builtin_amdgcn_s_setprio(1);
        #pragma unroll
        for (int f = 0; f < 4; ++f)
            #pragma unroll
            for (int g = 0; g < 2; ++g)
                #pragma unroll
                for (int ks = 0; ks < 2; ++ks)
                    acc[f][g] = __builtin_amdgcn_mfma_f32_16x16x32_bf16(
                        af[f][ks], bfr[g][ks], acc[f][g], 0, 0, 0);
        __builtin_amdgcn_s_setprio(0);
        __builtin_amdgcn_s_barrier();
        // ---------------- ph1: read B-half1 (4); MFMA Q(m0,n1)  (A cached)
        #pragma unroll
        for (int g = 2; g < 4; ++g) {
            int r = wn * 64 + g * 16 + (lane & 15);
            #pragma unroll
            for (int ks = 0; ks < 2; ++ks) {
                int cb = ks * 64 + (lane >> 4) * 16;
                bfr[g][ks] = *(const bf16x8*)(Bsb + r * 128 + (cb ^ ((r & 7) << 4)));
            }
        }
        __builtin_amdgcn_s_barrier();
        __builtin_amdgcn_s_setprio(1);
        #pragma unroll
        for (int f = 0; f < 4; ++f)
            #pragma unroll
            for (int g = 2; g < 4; ++g)
                #pragma unroll
                for (int ks = 0; ks < 2; ++ks)
                    acc[f][g] = __builtin_amdgcn_mfma_f32_16x16x32_bf16(
                        af[f][ks], bfr[g][ks], acc[f][g], 0, 0, 0);
        __builtin_amdgcn_s_setprio(0);
        __builtin_amdgcn_s_barrier();
        // ---------------- ph2: read A-half1 (8, overwrite af); stage next B;
        //                  MFMA Q(m1,n0)  (B-half0 cached)
        #pragma unroll
        for (int f = 0; f < 4; ++f) {
            int r = wm * 128 + 64 + f * 16 + (lane & 15);
            #pragma unroll
            for (int ks = 0; ks < 2; ++ks) {
                int cb = ks * 64 + (lane >> 4) * 16;
                af[f][ks] = *(const bf16x8*)(Asb + r * 128 + (cb ^ ((r & 7) << 4)));
            }
        }
        if (pf) {
            #pragma unroll
            for (int p = 0; p < 4; ++p) GLOAD16(Bsrc[p] + ko, pB + p * 4096 + t * 8);
        }
        __builtin_amdgcn_s_barrier();
        __builtin_amdgcn_s_setprio(1);
        #pragma unroll
        for (int f = 0; f < 4; ++f)
            #pragma unroll
            for (int g = 0; g < 2; ++g)
                #pragma unroll
                for (int ks = 0; ks < 2; ++ks)
                    acc[4 + f][g] = __builtin_amdgcn_mfma_f32_16x16x32_bf16(
                        af[f][ks], bfr[g][ks], acc[4 + f][g], 0, 0, 0);
        __builtin_amdgcn_s_setprio(0);
        __builtin_amdgcn_s_barrier();
        // ---------------- ph3: stage next A; MFMA Q(m1,n1)  (all cached)
        if (pf) {
            #pragma unroll
            for (int p = 0; p < 4; ++p) GLOAD16(Asrc[p] + ko, pA + p * 4096 + t * 8);
        }
        __builtin_amdgcn_s_setprio(1);
        #pragma unroll
        for (int f = 0; f < 4; ++f)
            #pragma unroll
            for (int g = 2; g < 4; ++g)
                #pragma unroll
                for (int ks = 0; ks < 2; ++ks)
                    acc[4 + f][g] = __builtin_amdgcn_mfma_f32_16x16x32_bf16(
                        af[f][ks], bfr[g][ks], acc[4 + f][g], 0, 0, 0);
        __builtin_amdgcn_s_setprio(0);
        // no trailing barrier: tile-top vmcnt+barrier follows
    }

    // epilogue: D layout col = lane&15, row = (lane>>4)*4 + reg
    #pragma unroll
    for (int f = 0; f < 8; ++f) {
        #pragma unroll
        for (int g = 0; g < 4; ++g) {
            int col = n0 + wn * 64 + g * 16 + (lane & 15);
            #pragma unroll
            for (int rg = 0; rg < 4; ++rg) {
                int row = m0 + wm * 128 + f * 16 + (lane >> 4) * 4 + rg;
                float bb = BIASROW ? bias[row] : bias[col];
                C[(size_t)row * N + col] = acc[f][g][rg] + bb;
            }
        }
    }
}

// ===========================================================================
// Kernel 4: fused q-chain + attn + out_win; emits bf16 Pb (= n_x + res_x_base)
// ===========================================================================
__global__ __launch_bounds__(256) void k_attn(
    const float* __restrict__ P, const float* __restrict__ b_buf, const float* __restrict__ b_rot,
    const float* __restrict__ qpw, const float* __restrict__ qpb,
    const float* __restrict__ nqg, const float* __restrict__ nqb,
    const float* __restrict__ qaw, const float* __restrict__ qab,
    const float* __restrict__ pos, __hip_bfloat16* __restrict__ Pb,
    float* __restrict__ attn_out)
{
    __shared__ float bs[16][4], brs[16][4];
    int t = threadIdx.x;
    int wh = blockIdx.y;
    int wi = wh >> 4, h = wh & 15;
    if (t < 64) {
        ((float*)bs)[t]  = b_buf[wh * 64 + t];
        ((float*)brs)[t] = b_rot[wh * 64 + t];
    }
    __syncthreads();
    int p = blockIdx.x * 256 + t;
    int wr = p >> 8, wc = p & 255;
    int gr = ((wi >> 1) << 8) + wr, gc = ((wi & 1) << 8) + wc;
    int y = gr >> 3, hnr = gr & 7, xq = gc >> 3, wnr = gc & 7;
    size_t base = (size_t)(y * 64 + xq) * 4096 + h * 256 + hnr * 8 + wnr;
    float r[4];
    #pragma unroll
    for (int d = 0; d < 4; ++d) r[d] = P[base + (size_t)d * 64];
    float mu = 0.25f * (r[0] + r[1] + r[2] + r[3]);
    float var = 0.25f * ((r[0]-mu)*(r[0]-mu) + (r[1]-mu)*(r[1]-mu) +
                         (r[2]-mu)*(r[2]-mu) + (r[3]-mu)*(r[3]-mu));
    float inv = rsqrtf(var + 1e-5f);
    float xh[4];
    #pragma unroll
    for (int d = 0; d < 4; ++d) xh[d] = (r[d] - mu) * inv * nqg[d] + nqb[d];
    float q4[4];
    #pragma unroll
    for (int d = 0; d < 4; ++d) {
        float a = qpb[d];
        #pragma unroll
        for (int e = 0; e < 4; ++e) a = fmaf(xh[e], qpw[d * 4 + e], a);
        q4[d] = a;
    }
    float z = qab[0];
    #pragma unroll
    for (int d = 0; d < 4; ++d) z = fmaf(q4[d], qaw[d], z);
    float gate = 1.0f / (1.0f + expf(-z));
    float4 pv = *(const float4*)(pos + ((size_t)h * 65536 + p) * 4);
    float v[4];
    v[0] = q4[0] * gate + pv.x * (1.0f - gate);
    v[1] = q4[1] * gate + pv.y * (1.0f - gate);
    v[2] = q4[2] * gate + pv.z * (1.0f - gate);
    v[3] = q4[3] * gate + pv.w * (1.0f - gate);
    float nn = sqrtf(v[0]*v[0] + v[1]*v[1] + v[2]*v[2] + v[3]*v[3]);
    float in2 = 1.0f / fmaxf(nn, 1e-12f);
    #pragma unroll
    for (int d = 0; d < 4; ++d) v[d] *= in2;
    float s0, c0, s1, c1;
    sincosf((float)wr, &s0, &c0);
    sincosf((float)wc, &s1, &c1);
    float qr[4];
    qr[0] = v[0] * c0 - v[1] * s0;
    qr[1] = v[0] * s0 + v[1] * c0;
    qr[2] = v[2] * c1 - v[3] * s1;
    qr[3] = v[2] * s1 + v[3] * c1;
    float arow[16];
    #pragma unroll
    for (int k = 0; k < 16; ++k)
        arow[k] = qr[0] * brs[k][0] + qr[1] * brs[k][1] + qr[2] * brs[k][2] + qr[3] * brs[k][3];
    size_t abase = ((size_t)wh * 65536 + p) * 16;
    #pragma unroll
    for (int kq = 0; kq < 4; ++kq) {
        float4 av;
        av.x = arow[kq * 4 + 0]; av.y = arow[kq * 4 + 1];
        av.z = arow[kq * 4 + 2]; av.w = arow[kq * 4 + 3];
        *(float4*)(attn_out + abase + kq * 4) = av;
    }
    float o[4] = {0.f, 0.f, 0.f, 0.f};
    #pragma unroll
    for (int k = 0; k < 16; ++k) {
        #pragma unroll
        for (int d = 0; d < 4; ++d) o[d] = fmaf(arow[k], bs[k][d], o[d]);
    }
    #pragma unroll
    for (int d = 0; d < 4; ++d)
        Pb[base + (size_t)d * 64] = __float2bfloat16(r[d] + o[d]);
}

// ===========================================================================
extern "C" void kernel_launch(void* const* d_in, const int* in_sizes, int n_in,
                              void* d_out, int out_size, void* d_ws, size_t ws_size,
                              hipStream_t stream)
{
    (void)in_sizes; (void)n_in; (void)out_size; (void)ws_size;
    const float* x    = (const float*)d_in[0];
    const float* xcw  = (const float*)d_in[1];
    const float* xcb  = (const float*)d_in[2];
    const float* rcw  = (const float*)d_in[3];
    const float* rcb  = (const float*)d_in[4];
    const float* pw   = (const float*)d_in[5];
    const float* pb   = (const float*)d_in[6];
    const float* bpw  = (const float*)d_in[7];
    const float* bpb  = (const float*)d_in[8];
    const float* qpw  = (const float*)d_in[9];
    const float* qpb  = (const float*)d_in[10];
    const float* nbg  = (const float*)d_in[11];
    const float* nbb  = (const float*)d_in[12];
    const float* nqg  = (const float*)d_in[13];
    const float* nqb  = (const float*)d_in[14];
    const float* qaw  = (const float*)d_in[15];
    const float* qab  = (const float*)d_in[16];
    const float* pos  = (const float*)d_in[17];
    const float* prw  = (const float*)d_in[18];
    const float* prb  = (const float*)d_in[19];

    float* ws = (float*)d_ws;
    __hip_bfloat16* abf  = (__hip_bfloat16*)d_ws;
    __hip_bfloat16* pwb  = (__hip_bfloat16*)d_ws + 67108864ull;
    float*          P    = ws + P_F;
    float*          b_buf = ws + BBUF_F;
    float*          b_rot = ws + BROT_F;
    __hip_bfloat16* Pb   = (__hip_bfloat16*)d_ws;                  // reuse abf
    __hip_bfloat16* prwb = (__hip_bfloat16*)d_ws + 67108864ull;    // reuse pwb
    float* out = (float*)d_out;

    k_bchain<<<1, 256, 0, stream>>>(x, xcw, xcb, bpw, bpb, nbg, nbb, b_buf, b_rot);
    k_resconv<<<4096, 256, 0, stream>>>(x, rcw, rcb, abf);
    k_cast_bf16<<<65536, 256, 0, stream>>>(pw, pwb, 67108864L);
    // patch conv: M = s(4096), N = co(4096), K = 16384; C = P[s][co], bias per col
    gemm_8p<0><<<dim3(16, 16), 512, 0, stream>>>(abf, pwb, pb, P, 4096, 4096, 16384);
    // fused q-chain / attn / out_win; emits bf16 Pb (into dead abf region)
    k_attn<<<dim3(256, 64), 256, 0, stream>>>(P, b_buf, b_rot, qpw, qpb, nqg, nqb,
                                              qaw, qab, pos, Pb, out + ATTN_OFF);
    k_cast_bf16<<<16384, 256, 0, stream>>>(prw, prwb, 16777216L);
    // 1x1 proj: M = co(4096), N = s(4096), K = 4096; C = out[co][s], bias per row
    gemm_8p<1><<<dim3(16, 16), 512, 0, stream>>>(prwb, Pb, prb, out, 4096, 4096, 4096);
}

// Round 5
// 567.101 us; speedup vs baseline: 15.4376x; 1.6449x over previous
//
#include <hip/hip_runtime.h>
#include <hip/hip_bf16.h>
#include <math.h>
#include <cstddef>

// ---------------------------------------------------------------------------
// Workspace (float offsets). Total ~151 MB.
//   Xmb   : bf16 [4096 s][1024 k]   floats [0 .. 2,097,152)
//   Cb    : bf16 [4096 co][1024 k]  floats [2,097,152 .. 4,194,304)
//   biasc : f32 [4096]              floats [4,194,304 ..)
//   b_buf : f32 [4096]              floats [4,198,400 ..)
//   b_rot : f32 [4096]              floats [4,202,496 ..)
//   P     : f32 [4096 s][4096 co]   floats [4,206,592 .. 20,983,808)
//   Pb    : bf16 [4096][4096]       floats [20,983,808 .. 29,372,416)
//   prwb  : bf16 [4096][4096]       floats [29,372,416 .. 37,761,024)
// k-index: k = ci*324 + m*18 + n  (ci<3, m<18, n<18; 972 real + 52 zero pad)
// ---------------------------------------------------------------------------
#define CB_F     2097152ull
#define BIASC_F  4194304ull
#define BBUF_F   4198400ull
#define BROT_F   4202496ull
#define P_F      4206592ull
#define PB_F     20983808ull
#define PRWB_F   29372416ull
#define ATTN_OFF 16777216ull

typedef __attribute__((ext_vector_type(8))) short bf16x8;
typedef __attribute__((ext_vector_type(4))) float f32x4;

#define GLOAD16(gsrc, ldst) \
  __builtin_amdgcn_global_load_lds((const __attribute__((address_space(1))) void*)(gsrc), \
                                   (__attribute__((address_space(3))) void*)(ldst), 16, 0, 0)

// ===========================================================================
// Kernel 1: x_feat conv + b-chain (LN, proj, l2, rope)
// ===========================================================================
__global__ __launch_bounds__(256) void k_bchain(
    const float* __restrict__ x, const float* __restrict__ xcw, const float* __restrict__ xcb,
    const float* __restrict__ bpw, const float* __restrict__ bpb,
    const float* __restrict__ nbg, const float* __restrict__ nbb,
    float* __restrict__ b_buf, float* __restrict__ b_rot)
{
    __shared__ float xs[3][8][8];
    __shared__ float xf[64][8][8];
    int t = threadIdx.x;
    if (t < 192) xs[t / 64][(t / 8) % 8][t % 8] = x[t];
    __syncthreads();
    for (int o = t; o < 4096; o += 256) {
        int c = o >> 6, i = (o >> 3) & 7, j = o & 7;
        float acc = xcb[c];
        for (int ic = 0; ic < 3; ++ic)
            for (int ky = 0; ky < 3; ++ky)
                for (int kx = 0; kx < 3; ++kx) {
                    int ii = i - 1 + ky, jj = j - 1 + kx;
                    if (ii >= 0 && ii < 8 && jj >= 0 && jj < 8)
                        acc = fmaf(xs[ic][ii][jj], xcw[((c * 3 + ic) * 3 + ky) * 3 + kx], acc);
                }
        xf[c][i][j] = acc;
    }
    __syncthreads();
    for (int idx = t; idx < 1024; idx += 256) {
        int wi = idx >> 8, h = (idx >> 4) & 15, pp = idx & 15;
        int pr = pp >> 2, pc = pp & 3;
        int gi = 4 * (wi >> 1) + pr, gj = 4 * (wi & 1) + pc;
        float v[4];
        #pragma unroll
        for (int d = 0; d < 4; ++d) v[d] = xf[h * 4 + d][gi][gj];
        float mu = 0.25f * (v[0] + v[1] + v[2] + v[3]);
        float var = 0.25f * ((v[0]-mu)*(v[0]-mu) + (v[1]-mu)*(v[1]-mu) +
                             (v[2]-mu)*(v[2]-mu) + (v[3]-mu)*(v[3]-mu));
        float inv = rsqrtf(var + 1e-5f);
        float xh[4];
        #pragma unroll
        for (int d = 0; d < 4; ++d) xh[d] = (v[d] - mu) * inv * nbg[d] + nbb[d];
        float bv[4];
        #pragma unroll
        for (int d = 0; d < 4; ++d) {
            float a = bpb[d];
            #pragma unroll
            for (int e = 0; e < 4; ++e) a = fmaf(xh[e], bpw[d * 4 + e], a);
            bv[d] = a;
        }
        #pragma unroll
        for (int d = 0; d < 4; ++d) b_buf[idx * 4 + d] = bv[d];
        float nn = sqrtf(bv[0]*bv[0] + bv[1]*bv[1] + bv[2]*bv[2] + bv[3]*bv[3]);
        float in2 = 1.0f / fmaxf(nn, 1e-12f);
        float bn[4];
        #pragma unroll
        for (int d = 0; d < 4; ++d) bn[d] = bv[d] * in2;
        float s0, c0, s1, c1;
        sincosf((float)pr, &s0, &c0);
        sincosf((float)pc, &s1, &c1);
        b_rot[idx * 4 + 0] = bn[0] * c0 - bn[1] * s0;
        b_rot[idx * 4 + 1] = bn[0] * s0 + bn[1] * c0;
        b_rot[idx * 4 + 2] = bn[2] * c1 - bn[3] * s1;
        b_rot[idx * 4 + 3] = bn[2] * s1 + bn[3] * c1;
    }
}

// ===========================================================================
// Kernel 2a: Xmap — A operand of the factorized patch GEMM.
// Xmb[s][k], k=(ci,m,n): zero-padded bilinear-resized x sampled at
// (16py+m-1, 16px+n-1). One block per s.
// ===========================================================================
__global__ __launch_bounds__(256) void k_xmap(
    const float* __restrict__ x, __hip_bfloat16* __restrict__ Xmb)
{
    __shared__ float xs[3][8][8];
    int t = threadIdx.x;
    if (t < 192) xs[t / 64][(t / 8) % 8][t % 8] = x[t];
    __syncthreads();
    int s = blockIdx.x, py = s >> 6, px = s & 63;
    __hip_bfloat16 out4[4];
    #pragma unroll
    for (int u = 0; u < 4; ++u) {
        int k = t * 4 + u;
        float val = 0.0f;
        if (k < 972) {
            int ci = k / 324, r = k % 324, m = r / 18, n = r % 18;
            int row = 16 * py + m - 1, col = 16 * px + n - 1;
            if (row >= 0 && row < 1024 && col >= 0 && col < 1024) {
                float fu = (row + 0.5f) * 0.0078125f - 0.5f;
                float fv = (col + 0.5f) * 0.0078125f - 0.5f;
                float fi = floorf(fu), fj = floorf(fv);
                float tu = fu - fi, tv = fv - fj;
                int i0 = (int)fi, j0 = (int)fj;
                int i0c = min(max(i0, 0), 7), i1c = min(max(i0 + 1, 0), 7);
                int j0c = min(max(j0, 0), 7), j1c = min(max(j0 + 1, 0), 7);
                val = (xs[ci][i0c][j0c] * (1.f - tv) + xs[ci][i0c][j1c] * tv) * (1.f - tu)
                    + (xs[ci][i1c][j0c] * (1.f - tv) + xs[ci][i1c][j1c] * tv) * tu;
            }
        }
        out4[u] = __float2bfloat16(val);
    }
    *(ushort4*)(Xmb + (size_t)s * 1024 + t * 4) = *(const ushort4*)out4;
}

// ===========================================================================
// Kernel 2b: C matrix — B operand. One block per co.
// C[co,ci,m,n] = sum_c sum_{ky,kx valid} rcw[c,ci,ky,kx] * pw[co,c,m-ky,n-kx]
// Also biasc[co] = pb[co] + sum_c rcb[c]*sum_{yx} pw[co,c,yx].
// Threads t<162: (m, n-pair). rcw reads are wave-uniform (scalar path).
// ===========================================================================
__global__ __launch_bounds__(256) void k_cmat(
    const float* __restrict__ pw, const float* __restrict__ rcw,
    const float* __restrict__ pb, const float* __restrict__ rcb,
    __hip_bfloat16* __restrict__ Cb, float* __restrict__ biasc)
{
    int co = blockIdx.x;
    const float* pwc = pw + (size_t)co * 16384;
    int t = threadIdx.x;
    __shared__ float red[256];
    // ---- bias: sum_c rcb[c]*pw[co,c,t]
    float bsum = 0.0f;
    for (int c = 0; c < 64; ++c) bsum += rcb[c] * pwc[c * 256 + t];
    red[t] = bsum;
    __syncthreads();
    for (int off = 128; off; off >>= 1) {
        if (t < off) red[t] += red[t + off];
        __syncthreads();
    }
    if (t == 0) biasc[co] = pb[co] + red[0];
    // ---- zero padding k in [972,1024)
    if (t >= 162 && t < 214) Cb[(size_t)co * 1024 + 972 + (t - 162)] = __float2bfloat16(0.0f);
    // ---- main correlation
    if (t < 162) {
        int m = t / 9, n0 = (t % 9) * 2;
        bool vlo = (n0 >= 2), vhi = (n0 <= 14);
        int rowoff[3]; bool rv[3];
        #pragma unroll
        for (int j = 0; j < 3; ++j) {
            int row = m - 2 + j;
            rv[j] = (row >= 0) && (row < 16);
            rowoff[j] = min(max(row, 0), 15) * 16;
        }
        int clo = max(n0 - 2, 0), chi = min(n0, 14);
        float acc[3][2] = {};
        for (int c = 0; c < 64; ++c) {
            const float* rp = pwc + c * 256;
            float seg[3][4];
            #pragma unroll
            for (int j = 0; j < 3; ++j) {
                float2 lo = *(const float2*)(rp + rowoff[j] + clo);
                float2 hi = *(const float2*)(rp + rowoff[j] + chi);
                bool okl = vlo && rv[j], okh = vhi && rv[j];
                seg[j][0] = okl ? lo.x : 0.0f;
                seg[j][1] = okl ? lo.y : 0.0f;
                seg[j][2] = okh ? hi.x : 0.0f;
                seg[j][3] = okh ? hi.y : 0.0f;
            }
            #pragma unroll
            for (int ky = 0; ky < 3; ++ky) {
                int j = 2 - ky;
                #pragma unroll
                for (int kx = 0; kx < 3; ++kx) {
                    #pragma unroll
                    for (int ci = 0; ci < 3; ++ci) {
                        float w = rcw[((c * 3 + ci) * 3 + ky) * 3 + kx];
                        acc[ci][0] = fmaf(w, seg[j][2 - kx], acc[ci][0]);
                        acc[ci][1] = fmaf(w, seg[j][3 - kx], acc[ci][1]);
                    }
                }
            }
        }
        size_t cb = (size_t)co * 1024;
        #pragma unroll
        for (int ci = 0; ci < 3; ++ci) {
            Cb[cb + ci * 324 + m * 18 + n0]     = __float2bfloat16(acc[ci][0]);
            Cb[cb + ci * 324 + m * 18 + n0 + 1] = __float2bfloat16(acc[ci][1]);
        }
    }
}

// ===========================================================================
__global__ __launch_bounds__(256) void k_cast_bf16(
    const float* __restrict__ in, __hip_bfloat16* __restrict__ out, long n)
{
    long i = ((long)blockIdx.x * 256 + threadIdx.x) * 4;
    if (i >= n) return;
    float4 v = *(const float4*)(in + i);
    __hip_bfloat16 h[4] = {__float2bfloat16(v.x), __float2bfloat16(v.y),
                           __float2bfloat16(v.z), __float2bfloat16(v.w)};
    *(ushort4*)(out + i) = *(const ushort4*)h;
}

// ===========================================================================
// 8-phase bf16 MFMA NT GEMM (m201 geometry), unchanged from round 3.
// BM=BN=256, BK=64, 8 waves (2Mx4N), wave tile 128x64, 2 LDS dbuf,
// counted vmcnt(8), 4 phases/K-tile, register-cached fragments, T2 swizzle.
// ===========================================================================
template <int BIASROW>
__global__ __launch_bounds__(512) void gemm_8p(
    const __hip_bfloat16* __restrict__ A, const __hip_bfloat16* __restrict__ B,
    const float* __restrict__ bias, float* __restrict__ C,
    int M, int N, int K)
{
    __shared__ short lds[65536];
    const short* Ag = (const short*)A;
    const short* Bg = (const short*)B;
    int t = threadIdx.x;
    int lane = t & 63;
    int wid = t >> 6;
    int wm = wid >> 2, wn = wid & 3;

    int nwg = gridDim.x * gridDim.y;
    int flat = blockIdx.y * gridDim.x + blockIdx.x;
    int swz = (flat & 7) * (nwg >> 3) + (flat >> 3);
    int bx = swz % gridDim.x, by = swz / gridDim.x;
    int m0 = by * 256, n0 = bx * 256;
    int T = K >> 6;

    int srow = t >> 3;
    int sc = ((t & 7) ^ (srow & 7)) * 8;
    const short* Asrc[4]; const short* Bsrc[4];
    #pragma unroll
    for (int p = 0; p < 4; ++p) {
        Asrc[p] = Ag + (size_t)(m0 + p * 64 + srow) * K + sc;
        Bsrc[p] = Bg + (size_t)(n0 + p * 64 + srow) * K + sc;
    }

    f32x4 acc[8][4] = {};

    #pragma unroll
    for (int u = 0; u < 2; ++u) {
        short* bA = lds + u * 32768;
        short* bB = bA + 16384;
        size_t ko = (size_t)u * 64;
        #pragma unroll
        for (int p = 0; p < 4; ++p) GLOAD16(Asrc[p] + ko, bA + p * 4096 + t * 8);
        #pragma unroll
        for (int p = 0; p < 4; ++p) GLOAD16(Bsrc[p] + ko, bB + p * 4096 + t * 8);
    }

    for (int tt = 0; tt < T; ++tt) {
        if (tt + 1 < T) { asm volatile("s_waitcnt vmcnt(8)" ::: "memory"); }
        else            { asm volatile("s_waitcnt vmcnt(0)" ::: "memory"); }
        __builtin_amdgcn_s_barrier();
        __builtin_amdgcn_sched_barrier(0);

        const char* Asb = (const char*)(lds + (tt & 1) * 32768);
        const char* Bsb = Asb + 32768;
        short* pA = lds + (tt & 1) * 32768;
        short* pB = pA + 16384;
        bool pf = (tt + 2) < T;
        size_t ko = (size_t)(tt + 2) * 64;

        bf16x8 af[4][2], bfr[4][2];
        // ph0
        #pragma unroll
        for (int f = 0; f < 4; ++f) {
            int r = wm * 128 + f * 16 + (lane & 15);
            #pragma unroll
            for (int ks = 0; ks < 2; ++ks) {
                int cb = ks * 64 + (lane >> 4) * 16;
                af[f][ks] = *(const bf16x8*)(Asb + r * 128 + (cb ^ ((r & 7) << 4)));
            }
        }
        #pragma unroll
        for (int g = 0; g < 2; ++g) {
            int r = wn * 64 + g * 16 + (lane & 15);
            #pragma unroll
            for (int ks = 0; ks < 2; ++ks) {
                int cb = ks * 64 + (lane >> 4) * 16;
                bfr[g][ks] = *(const bf16x8*)(Bsb + r * 128 + (cb ^ ((r & 7) << 4)));
            }
        }
        __builtin_amdgcn_s_barrier();
        __builtin_amdgcn_s_setprio(1);
        #pragma unroll
        for (int f = 0; f < 4; ++f)
            #pragma unroll
            for (int g = 0; g < 2; ++g)
                #pragma unroll
                for (int ks = 0; ks < 2; ++ks)
                    acc[f][g] = __builtin_amdgcn_mfma_f32_16x16x32_bf16(
                        af[f][ks], bfr[g][ks], acc[f][g], 0, 0, 0);
        __builtin_amdgcn_s_setprio(0);
        __builtin_amdgcn_s_barrier();
        // ph1
        #pragma unroll
        for (int g = 2; g < 4; ++g) {
            int r = wn * 64 + g * 16 + (lane & 15);
            #pragma unroll
            for (int ks = 0; ks < 2; ++ks) {
                int cb = ks * 64 + (lane >> 4) * 16;
                bfr[g][ks] = *(const bf16x8*)(Bsb + r * 128 + (cb ^ ((r & 7) << 4)));
            }
        }
        __builtin_amdgcn_s_barrier();
        __builtin_amdgcn_s_setprio(1);
        #pragma unroll
        for (int f = 0; f < 4; ++f)
            #pragma unroll
            for (int g = 2; g < 4; ++g)
                #pragma unroll
                for (int ks = 0; ks < 2; ++ks)
                    acc[f][g] = __builtin_amdgcn_mfma_f32_16x16x32_bf16(
                        af[f][ks], bfr[g][ks], acc[f][g], 0, 0, 0);
        __builtin_amdgcn_s_setprio(0);
        __builtin_amdgcn_s_barrier();
        // ph2
        #pragma unroll
        for (int f = 0; f < 4; ++f) {
            int r = wm * 128 + 64 + f * 16 + (lane & 15);
            #pragma unroll
            for (int ks = 0; ks < 2; ++ks) {
                int cb = ks * 64 + (lane >> 4) * 16;
                af[f][ks] = *(const bf16x8*)(Asb + r * 128 + (cb ^ ((r & 7) << 4)));
            }
        }
        if (pf) {
            #pragma unroll
            for (int p = 0; p < 4; ++p) GLOAD16(Bsrc[p] + ko, pB + p * 4096 + t * 8);
        }
        __builtin_amdgcn_s_barrier();
        __builtin_amdgcn_s_setprio(1);
        #pragma unroll
        for (int f = 0; f < 4; ++f)
            #pragma unroll
            for (int g = 0; g < 2; ++g)
                #pragma unroll
                for (int ks = 0; ks < 2; ++ks)
                    acc[4 + f][g] = __builtin_amdgcn_mfma_f32_16x16x32_bf16(
                        af[f][ks], bfr[g][ks], acc[4 + f][g], 0, 0, 0);
        __builtin_amdgcn_s_setprio(0);
        __builtin_amdgcn_s_barrier();
        // ph3
        if (pf) {
            #pragma unroll
            for (int p = 0; p < 4; ++p) GLOAD16(Asrc[p] + ko, pA + p * 4096 + t * 8);
        }
        __builtin_amdgcn_s_setprio(1);
        #pragma unroll
        for (int f = 0; f < 4; ++f)
            #pragma unroll
            for (int g = 2; g < 4; ++g)
                #pragma unroll
                for (int ks = 0; ks < 2; ++ks)
                    acc[4 + f][g] = __builtin_amdgcn_mfma_f32_16x16x32_bf16(
                        af[f][ks], bfr[g][ks], acc[4 + f][g], 0, 0, 0);
        __builtin_amdgcn_s_setprio(0);
    }

    #pragma unroll
    for (int f = 0; f < 8; ++f) {
        #pragma unroll
        for (int g = 0; g < 4; ++g) {
            int col = n0 + wn * 64 + g * 16 + (lane & 15);
            #pragma unroll
            for (int rg = 0; rg < 4; ++rg) {
                int row = m0 + wm * 128 + f * 16 + (lane >> 4) * 4 + rg;
                float bb = BIASROW ? bias[row] : bias[col];
                C[(size_t)row * N + col] = acc[f][g][rg] + bb;
            }
        }
    }
}

// ===========================================================================
// Kernel 4: fused q-chain + attn + out_win; emits bf16 Pb (= n_x + res_x_base)
// ===========================================================================
__global__ __launch_bounds__(256) void k_attn(
    const float* __restrict__ P, const float* __restrict__ b_buf, const float* __restrict__ b_rot,
    const float* __restrict__ qpw, const float* __restrict__ qpb,
    const float* __restrict__ nqg, const float* __restrict__ nqb,
    const float* __restrict__ qaw, const float* __restrict__ qab,
    const float* __restrict__ pos, __hip_bfloat16* __restrict__ Pb,
    float* __restrict__ attn_out)
{
    __shared__ float bs[16][4], brs[16][4];
    int t = threadIdx.x;
    int wh = blockIdx.y;
    int wi = wh >> 4, h = wh & 15;
    if (t < 64) {
        ((float*)bs)[t]  = b_buf[wh * 64 + t];
        ((float*)brs)[t] = b_rot[wh * 64 + t];
    }
    __syncthreads();
    int p = blockIdx.x * 256 + t;
    int wr = p >> 8, wc = p & 255;
    int gr = ((wi >> 1) << 8) + wr, gc = ((wi & 1) << 8) + wc;
    int y = gr >> 3, hnr = gr & 7, xq = gc >> 3, wnr = gc & 7;
    size_t base = (size_t)(y * 64 + xq) * 4096 + h * 256 + hnr * 8 + wnr;
    float r[4];
    #pragma unroll
    for (int d = 0; d < 4; ++d) r[d] = P[base + (size_t)d * 64];
    float mu = 0.25f * (r[0] + r[1] + r[2] + r[3]);
    float var = 0.25f * ((r[0]-mu)*(r[0]-mu) + (r[1]-mu)*(r[1]-mu) +
                         (r[2]-mu)*(r[2]-mu) + (r[3]-mu)*(r[3]-mu));
    float inv = rsqrtf(var + 1e-5f);
    float xh[4];
    #pragma unroll
    for (int d = 0; d < 4; ++d) xh[d] = (r[d] - mu) * inv * nqg[d] + nqb[d];
    float q4[4];
    #pragma unroll
    for (int d = 0; d < 4; ++d) {
        float a = qpb[d];
        #pragma unroll
        for (int e = 0; e < 4; ++e) a = fmaf(xh[e], qpw[d * 4 + e], a);
        q4[d] = a;
    }
    float z = qab[0];
    #pragma unroll
    for (int d = 0; d < 4; ++d) z = fmaf(q4[d], qaw[d], z);
    float gate = 1.0f / (1.0f + expf(-z));
    float4 pv = *(const float4*)(pos + ((size_t)h * 65536 + p) * 4);
    float v[4];
    v[0] = q4[0] * gate + pv.x * (1.0f - gate);
    v[1] = q4[1] * gate + pv.y * (1.0f - gate);
    v[2] = q4[2] * gate + pv.z * (1.0f - gate);
    v[3] = q4[3] * gate + pv.w * (1.0f - gate);
    float nn = sqrtf(v[0]*v[0] + v[1]*v[1] + v[2]*v[2] + v[3]*v[3]);
    float in2 = 1.0f / fmaxf(nn, 1e-12f);
    #pragma unroll
    for (int d = 0; d < 4; ++d) v[d] *= in2;
    float s0, c0, s1, c1;
    sincosf((float)wr, &s0, &c0);
    sincosf((float)wc, &s1, &c1);
    float qr[4];
    qr[0] = v[0] * c0 - v[1] * s0;
    qr[1] = v[0] * s0 + v[1] * c0;
    qr[2] = v[2] * c1 - v[3] * s1;
    qr[3] = v[2] * s1 + v[3] * c1;
    float arow[16];
    #pragma unroll
    for (int k = 0; k < 16; ++k)
        arow[k] = qr[0] * brs[k][0] + qr[1] * brs[k][1] + qr[2] * brs[k][2] + qr[3] * brs[k][3];
    size_t abase = ((size_t)wh * 65536 + p) * 16;
    #pragma unroll
    for (int kq = 0; kq < 4; ++kq) {
        float4 av;
        av.x = arow[kq * 4 + 0]; av.y = arow[kq * 4 + 1];
        av.z = arow[kq * 4 + 2]; av.w = arow[kq * 4 + 3];
        *(float4*)(attn_out + abase + kq * 4) = av;
    }
    float o[4] = {0.f, 0.f, 0.f, 0.f};
    #pragma unroll
    for (int k = 0; k < 16; ++k) {
        #pragma unroll
        for (int d = 0; d < 4; ++d) o[d] = fmaf(arow[k], bs[k][d], o[d]);
    }
    #pragma unroll
    for (int d = 0; d < 4; ++d)
        Pb[base + (size_t)d * 64] = __float2bfloat16(r[d] + o[d]);
}

// ===========================================================================
extern "C" void kernel_launch(void* const* d_in, const int* in_sizes, int n_in,
                              void* d_out, int out_size, void* d_ws, size_t ws_size,
                              hipStream_t stream)
{
    (void)in_sizes; (void)n_in; (void)out_size; (void)ws_size;
    const float* x    = (const float*)d_in[0];
    const float* xcw  = (const float*)d_in[1];
    const float* xcb  = (const float*)d_in[2];
    const float* rcw  = (const float*)d_in[3];
    const float* rcb  = (const float*)d_in[4];
    const float* pw   = (const float*)d_in[5];
    const float* pb   = (const float*)d_in[6];
    const float* bpw  = (const float*)d_in[7];
    const float* bpb  = (const float*)d_in[8];
    const float* qpw  = (const float*)d_in[9];
    const float* qpb  = (const float*)d_in[10];
    const float* nbg  = (const float*)d_in[11];
    const float* nbb  = (const float*)d_in[12];
    const float* nqg  = (const float*)d_in[13];
    const float* nqb  = (const float*)d_in[14];
    const float* qaw  = (const float*)d_in[15];
    const float* qab  = (const float*)d_in[16];
    const float* pos  = (const float*)d_in[17];
    const float* prw  = (const float*)d_in[18];
    const float* prb  = (const float*)d_in[19];

    float* ws = (float*)d_ws;
    __hip_bfloat16* Xmb   = (__hip_bfloat16*)d_ws;
    __hip_bfloat16* Cb    = (__hip_bfloat16*)(ws + CB_F);
    float*          biasc = ws + BIASC_F;
    float*          b_buf = ws + BBUF_F;
    float*          b_rot = ws + BROT_F;
    float*          P     = ws + P_F;
    __hip_bfloat16* Pb    = (__hip_bfloat16*)(ws + PB_F);
    __hip_bfloat16* prwb  = (__hip_bfloat16*)(ws + PRWB_F);
    float* out = (float*)d_out;

    k_bchain<<<1, 256, 0, stream>>>(x, xcw, xcb, bpw, bpb, nbg, nbb, b_buf, b_rot);
    k_xmap<<<4096, 256, 0, stream>>>(x, Xmb);
    k_cmat<<<4096, 256, 0, stream>>>(pw, rcw, pb, rcb, Cb, biasc);
    // factorized patch conv: M = s(4096), N = co(4096), K = 1024 (972 real)
    gemm_8p<0><<<dim3(16, 16), 512, 0, stream>>>(Xmb, Cb, biasc, P, 4096, 4096, 1024);
    // fused q-chain / attn / out_win; emits bf16 Pb
    k_attn<<<dim3(256, 64), 256, 0, stream>>>(P, b_buf, b_rot, qpw, qpb, nqg, nqb,
                                              qaw, qab, pos, Pb, out + ATTN_OFF);
    k_cast_bf16<<<16384, 256, 0, stream>>>(prw, prwb, 16777216L);
    // 1x1 proj: M = co(4096), N = s(4096), K = 4096; C = out[co][s], bias per row
    gemm_8p<1><<<dim3(16, 16), 512, 0, stream>>>(prwb, Pb, prb, out, 4096, 4096, 4096);
}

// Round 6
// 521.475 us; speedup vs baseline: 16.7883x; 1.0875x over previous
//
#include <hip/hip_runtime.h>
#include <hip/hip_bf16.h>
#include <math.h>
#include <cstddef>

// ---------------------------------------------------------------------------
// Workspace (float offsets). Total ~151 MB.
//   Xmb   : bf16 [4096 s][1024 k]   floats [0 .. 2,097,152)
//   Cb    : bf16 [4096 co][1024 k]  floats [2,097,152 .. 4,194,304)
//   biasc : f32 [4096]              floats [4,194,304 ..)
//   b_buf : f32 [4096]              floats [4,198,400 ..)
//   b_rot : f32 [4096]              floats [4,202,496 ..)
//   P     : f32 [4096 s][4096 co]   floats [4,206,592 .. 20,983,808)
//   Pb    : bf16 [4096][4096]       floats [20,983,808 .. 29,372,416)
//   prwb  : bf16 [4096][4096]       floats [29,372,416 .. 37,761,024)
// k-index: k = ci*324 + m*18 + n  (ci<3, m<18, n<18; 972 real + 52 zero pad)
// ---------------------------------------------------------------------------
#define CB_F     2097152ull
#define BIASC_F  4194304ull
#define BBUF_F   4198400ull
#define BROT_F   4202496ull
#define P_F      4206592ull
#define PB_F     20983808ull
#define PRWB_F   29372416ull
#define ATTN_OFF 16777216ull

typedef __attribute__((ext_vector_type(8))) short bf16x8;
typedef __attribute__((ext_vector_type(4))) float f32x4;

#define GLOAD16(gsrc, ldst) \
  __builtin_amdgcn_global_load_lds((const __attribute__((address_space(1))) void*)(gsrc), \
                                   (__attribute__((address_space(3))) void*)(ldst), 16, 0, 0)

// ===========================================================================
// Kernel 1: x_feat conv + b-chain (LN, proj, l2, rope)
// ===========================================================================
__global__ __launch_bounds__(256) void k_bchain(
    const float* __restrict__ x, const float* __restrict__ xcw, const float* __restrict__ xcb,
    const float* __restrict__ bpw, const float* __restrict__ bpb,
    const float* __restrict__ nbg, const float* __restrict__ nbb,
    float* __restrict__ b_buf, float* __restrict__ b_rot)
{
    __shared__ float xs[3][8][8];
    __shared__ float xf[64][8][8];
    int t = threadIdx.x;
    if (t < 192) xs[t / 64][(t / 8) % 8][t % 8] = x[t];
    __syncthreads();
    for (int o = t; o < 4096; o += 256) {
        int c = o >> 6, i = (o >> 3) & 7, j = o & 7;
        float acc = xcb[c];
        for (int ic = 0; ic < 3; ++ic)
            for (int ky = 0; ky < 3; ++ky)
                for (int kx = 0; kx < 3; ++kx) {
                    int ii = i - 1 + ky, jj = j - 1 + kx;
                    if (ii >= 0 && ii < 8 && jj >= 0 && jj < 8)
                        acc = fmaf(xs[ic][ii][jj], xcw[((c * 3 + ic) * 3 + ky) * 3 + kx], acc);
                }
        xf[c][i][j] = acc;
    }
    __syncthreads();
    for (int idx = t; idx < 1024; idx += 256) {
        int wi = idx >> 8, h = (idx >> 4) & 15, pp = idx & 15;
        int pr = pp >> 2, pc = pp & 3;
        int gi = 4 * (wi >> 1) + pr, gj = 4 * (wi & 1) + pc;
        float v[4];
        #pragma unroll
        for (int d = 0; d < 4; ++d) v[d] = xf[h * 4 + d][gi][gj];
        float mu = 0.25f * (v[0] + v[1] + v[2] + v[3]);
        float var = 0.25f * ((v[0]-mu)*(v[0]-mu) + (v[1]-mu)*(v[1]-mu) +
                             (v[2]-mu)*(v[2]-mu) + (v[3]-mu)*(v[3]-mu));
        float inv = rsqrtf(var + 1e-5f);
        float xh[4];
        #pragma unroll
        for (int d = 0; d < 4; ++d) xh[d] = (v[d] - mu) * inv * nbg[d] + nbb[d];
        float bv[4];
        #pragma unroll
        for (int d = 0; d < 4; ++d) {
            float a = bpb[d];
            #pragma unroll
            for (int e = 0; e < 4; ++e) a = fmaf(xh[e], bpw[d * 4 + e], a);
            bv[d] = a;
        }
        #pragma unroll
        for (int d = 0; d < 4; ++d) b_buf[idx * 4 + d] = bv[d];
        float nn = sqrtf(bv[0]*bv[0] + bv[1]*bv[1] + bv[2]*bv[2] + bv[3]*bv[3]);
        float in2 = 1.0f / fmaxf(nn, 1e-12f);
        float bn[4];
        #pragma unroll
        for (int d = 0; d < 4; ++d) bn[d] = bv[d] * in2;
        float s0, c0, s1, c1;
        sincosf((float)pr, &s0, &c0);
        sincosf((float)pc, &s1, &c1);
        b_rot[idx * 4 + 0] = bn[0] * c0 - bn[1] * s0;
        b_rot[idx * 4 + 1] = bn[0] * s0 + bn[1] * c0;
        b_rot[idx * 4 + 2] = bn[2] * c1 - bn[3] * s1;
        b_rot[idx * 4 + 3] = bn[2] * s1 + bn[3] * c1;
    }
}

// ===========================================================================
// Kernel 2a: Xmap — A operand of the factorized patch GEMM.
// ===========================================================================
__global__ __launch_bounds__(256) void k_xmap(
    const float* __restrict__ x, __hip_bfloat16* __restrict__ Xmb)
{
    __shared__ float xs[3][8][8];
    int t = threadIdx.x;
    if (t < 192) xs[t / 64][(t / 8) % 8][t % 8] = x[t];
    __syncthreads();
    int s = blockIdx.x, py = s >> 6, px = s & 63;
    __hip_bfloat16 out4[4];
    #pragma unroll
    for (int u = 0; u < 4; ++u) {
        int k = t * 4 + u;
        float val = 0.0f;
        if (k < 972) {
            int ci = k / 324, r = k % 324, m = r / 18, n = r % 18;
            int row = 16 * py + m - 1, col = 16 * px + n - 1;
            if (row >= 0 && row < 1024 && col >= 0 && col < 1024) {
                float fu = (row + 0.5f) * 0.0078125f - 0.5f;
                float fv = (col + 0.5f) * 0.0078125f - 0.5f;
                float fi = floorf(fu), fj = floorf(fv);
                float tu = fu - fi, tv = fv - fj;
                int i0 = (int)fi, j0 = (int)fj;
                int i0c = min(max(i0, 0), 7), i1c = min(max(i0 + 1, 0), 7);
                int j0c = min(max(j0, 0), 7), j1c = min(max(j0 + 1, 0), 7);
                val = (xs[ci][i0c][j0c] * (1.f - tv) + xs[ci][i0c][j1c] * tv) * (1.f - tu)
                    + (xs[ci][i1c][j0c] * (1.f - tv) + xs[ci][i1c][j1c] * tv) * tu;
            }
        }
        out4[u] = __float2bfloat16(val);
    }
    *(ushort4*)(Xmb + (size_t)s * 1024 + t * 4) = *(const ushort4*)out4;
}

// ===========================================================================
// Kernel 2b v2: C matrix. One block per co.
// LDS-staged, zero-padded pw tile -> mask-free correlation; bias fused into
// the staging pass. C[co,ci,m,n] = sum_{c,ky,kx} rcw[c,ci,ky,kx]*pwpad[m-ky][n-kx]
// ===========================================================================
__global__ __launch_bounds__(256) void k_cmat(
    const float* __restrict__ pw, const float* __restrict__ rcw,
    const float* __restrict__ pb, const float* __restrict__ rcb,
    __hip_bfloat16* __restrict__ Cb, float* __restrict__ biasc)
{
    __shared__ float rcw_s[64 * 28];     // [c][27] padded to 28
    __shared__ float rcb_s[64];
    __shared__ float pwp[8][20][20];     // zero-padded chunk of pw[co]
    __shared__ float red[256];
    int co = blockIdx.x;
    const float* pwc = pw + (size_t)co * 16384;
    int t = threadIdx.x;

    // stage rcw / rcb; zero pwp borders (zero whole tile once: interior is
    // overwritten every chunk, borders stay zero)
    #pragma unroll
    for (int i = 0; i < 7; ++i) {
        int idx = i * 256 + t;
        if (idx < 1728) rcw_s[(idx / 27) * 28 + (idx % 27)] = rcw[idx];
    }
    if (t < 64) rcb_s[t] = rcb[t];
    for (int i = t; i < 3200; i += 256) ((float*)pwp)[i] = 0.0f;

    int m = t / 9, n0 = (t % 9) * 2;     // valid for t < 162
    float acc[3][2] = {};
    float bsum = 0.0f;

    for (int c0 = 0; c0 < 64; c0 += 8) {
        __syncthreads();                 // previous compute done (and init done)
        #pragma unroll
        for (int i = 0; i < 8; ++i) {
            float v = pwc[(c0 + i) * 256 + t];
            pwp[i][(t >> 4) + 2][(t & 15) + 2] = v;
            bsum = fmaf(rcb_s[c0 + i], v, bsum);
        }
        __syncthreads();
        if (t < 162) {
            #pragma unroll
            for (int cl = 0; cl < 8; ++cl) {
                float seg[3][4];
                #pragma unroll
                for (int j = 0; j < 3; ++j) {
                    float2 lo = *(const float2*)&pwp[cl][m + j][n0];
                    float2 hi = *(const float2*)&pwp[cl][m + j][n0 + 2];
                    seg[j][0] = lo.x; seg[j][1] = lo.y;
                    seg[j][2] = hi.x; seg[j][3] = hi.y;
                }
                const float* rw = &rcw_s[(c0 + cl) * 28];
                #pragma unroll
                for (int ci = 0; ci < 3; ++ci)
                    #pragma unroll
                    for (int ky = 0; ky < 3; ++ky) {
                        int j = 2 - ky;
                        #pragma unroll
                        for (int kx = 0; kx < 3; ++kx) {
                            float w = rw[ci * 9 + ky * 3 + kx];
                            acc[ci][0] = fmaf(w, seg[j][2 - kx], acc[ci][0]);
                            acc[ci][1] = fmaf(w, seg[j][3 - kx], acc[ci][1]);
                        }
                    }
            }
        }
    }

    // bias reduction
    red[t] = bsum;
    __syncthreads();
    for (int off = 128; off; off >>= 1) {
        if (t < off) red[t] += red[t + off];
        __syncthreads();
    }
    if (t == 0) biasc[co] = pb[co] + red[0];
    // zero padding k in [972,1024)
    if (t >= 162 && t < 214) Cb[(size_t)co * 1024 + 972 + (t - 162)] = __float2bfloat16(0.0f);
    // write outputs
    if (t < 162) {
        size_t cb = (size_t)co * 1024;
        #pragma unroll
        for (int ci = 0; ci < 3; ++ci) {
            Cb[cb + ci * 324 + m * 18 + n0]     = __float2bfloat16(acc[ci][0]);
            Cb[cb + ci * 324 + m * 18 + n0 + 1] = __float2bfloat16(acc[ci][1]);
        }
    }
}

// ===========================================================================
__global__ __launch_bounds__(256) void k_cast_bf16(
    const float* __restrict__ in, __hip_bfloat16* __restrict__ out, long n)
{
    long i = ((long)blockIdx.x * 256 + threadIdx.x) * 4;
    if (i >= n) return;
    float4 v = *(const float4*)(in + i);
    __hip_bfloat16 h[4] = {__float2bfloat16(v.x), __float2bfloat16(v.y),
                           __float2bfloat16(v.z), __float2bfloat16(v.w)};
    *(ushort4*)(out + i) = *(const ushort4*)h;
}

// ===========================================================================
// 8-phase bf16 MFMA NT GEMM (m201 geometry), unchanged.
// ===========================================================================
template <int BIASROW>
__global__ __launch_bounds__(512) void gemm_8p(
    const __hip_bfloat16* __restrict__ A, const __hip_bfloat16* __restrict__ B,
    const float* __restrict__ bias, float* __restrict__ C,
    int M, int N, int K)
{
    __shared__ short lds[65536];
    const short* Ag = (const short*)A;
    const short* Bg = (const short*)B;
    int t = threadIdx.x;
    int lane = t & 63;
    int wid = t >> 6;
    int wm = wid >> 2, wn = wid & 3;

    int nwg = gridDim.x * gridDim.y;
    int flat = blockIdx.y * gridDim.x + blockIdx.x;
    int swz = (flat & 7) * (nwg >> 3) + (flat >> 3);
    int bx = swz % gridDim.x, by = swz / gridDim.x;
    int m0 = by * 256, n0 = bx * 256;
    int T = K >> 6;

    int srow = t >> 3;
    int sc = ((t & 7) ^ (srow & 7)) * 8;
    const short* Asrc[4]; const short* Bsrc[4];
    #pragma unroll
    for (int p = 0; p < 4; ++p) {
        Asrc[p] = Ag + (size_t)(m0 + p * 64 + srow) * K + sc;
        Bsrc[p] = Bg + (size_t)(n0 + p * 64 + srow) * K + sc;
    }

    f32x4 acc[8][4] = {};

    #pragma unroll
    for (int u = 0; u < 2; ++u) {
        short* bA = lds + u * 32768;
        short* bB = bA + 16384;
        size_t ko = (size_t)u * 64;
        #pragma unroll
        for (int p = 0; p < 4; ++p) GLOAD16(Asrc[p] + ko, bA + p * 4096 + t * 8);
        #pragma unroll
        for (int p = 0; p < 4; ++p) GLOAD16(Bsrc[p] + ko, bB + p * 4096 + t * 8);
    }

    for (int tt = 0; tt < T; ++tt) {
        if (tt + 1 < T) { asm volatile("s_waitcnt vmcnt(8)" ::: "memory"); }
        else            { asm volatile("s_waitcnt vmcnt(0)" ::: "memory"); }
        __builtin_amdgcn_s_barrier();
        __builtin_amdgcn_sched_barrier(0);

        const char* Asb = (const char*)(lds + (tt & 1) * 32768);
        const char* Bsb = Asb + 32768;
        short* pA = lds + (tt & 1) * 32768;
        short* pB = pA + 16384;
        bool pf = (tt + 2) < T;
        size_t ko = (size_t)(tt + 2) * 64;

        bf16x8 af[4][2], bfr[4][2];
        // ph0
        #pragma unroll
        for (int f = 0; f < 4; ++f) {
            int r = wm * 128 + f * 16 + (lane & 15);
            #pragma unroll
            for (int ks = 0; ks < 2; ++ks) {
                int cb = ks * 64 + (lane >> 4) * 16;
                af[f][ks] = *(const bf16x8*)(Asb + r * 128 + (cb ^ ((r & 7) << 4)));
            }
        }
        #pragma unroll
        for (int g = 0; g < 2; ++g) {
            int r = wn * 64 + g * 16 + (lane & 15);
            #pragma unroll
            for (int ks = 0; ks < 2; ++ks) {
                int cb = ks * 64 + (lane >> 4) * 16;
                bfr[g][ks] = *(const bf16x8*)(Bsb + r * 128 + (cb ^ ((r & 7) << 4)));
            }
        }
        __builtin_amdgcn_s_barrier();
        __builtin_amdgcn_s_setprio(1);
        #pragma unroll
        for (int f = 0; f < 4; ++f)
            #pragma unroll
            for (int g = 0; g < 2; ++g)
                #pragma unroll
                for (int ks = 0; ks < 2; ++ks)
                    acc[f][g] = __builtin_amdgcn_mfma_f32_16x16x32_bf16(
                        af[f][ks], bfr[g][ks], acc[f][g], 0, 0, 0);
        __builtin_amdgcn_s_setprio(0);
        __builtin_amdgcn_s_barrier();
        // ph1
        #pragma unroll
        for (int g = 2; g < 4; ++g) {
            int r = wn * 64 + g * 16 + (lane & 15);
            #pragma unroll
            for (int ks = 0; ks < 2; ++ks) {
                int cb = ks * 64 + (lane >> 4) * 16;
                bfr[g][ks] = *(const bf16x8*)(Bsb + r * 128 + (cb ^ ((r & 7) << 4)));
            }
        }
        __builtin_amdgcn_s_barrier();
        __builtin_amdgcn_s_setprio(1);
        #pragma unroll
        for (int f = 0; f < 4; ++f)
            #pragma unroll
            for (int g = 2; g < 4; ++g)
                #pragma unroll
                for (int ks = 0; ks < 2; ++ks)
                    acc[f][g] = __builtin_amdgcn_mfma_f32_16x16x32_bf16(
                        af[f][ks], bfr[g][ks], acc[f][g], 0, 0, 0);
        __builtin_amdgcn_s_setprio(0);
        __builtin_amdgcn_s_barrier();
        // ph2
        #pragma unroll
        for (int f = 0; f < 4; ++f) {
            int r = wm * 128 + 64 + f * 16 + (lane & 15);
            #pragma unroll
            for (int ks = 0; ks < 2; ++ks) {
                int cb = ks * 64 + (lane >> 4) * 16;
                af[f][ks] = *(const bf16x8*)(Asb + r * 128 + (cb ^ ((r & 7) << 4)));
            }
        }
        if (pf) {
            #pragma unroll
            for (int p = 0; p < 4; ++p) GLOAD16(Bsrc[p] + ko, pB + p * 4096 + t * 8);
        }
        __builtin_amdgcn_s_barrier();
        __builtin_amdgcn_s_setprio(1);
        #pragma unroll
        for (int f = 0; f < 4; ++f)
            #pragma unroll
            for (int g = 0; g < 2; ++g)
                #pragma unroll
                for (int ks = 0; ks < 2; ++ks)
                    acc[4 + f][g] = __builtin_amdgcn_mfma_f32_16x16x32_bf16(
                        af[f][ks], bfr[g][ks], acc[4 + f][g], 0, 0, 0);
        __builtin_amdgcn_s_setprio(0);
        __builtin_amdgcn_s_barrier();
        // ph3
        if (pf) {
            #pragma unroll
            for (int p = 0; p < 4; ++p) GLOAD16(Asrc[p] + ko, pA + p * 4096 + t * 8);
        }
        __builtin_amdgcn_s_setprio(1);
        #pragma unroll
        for (int f = 0; f < 4; ++f)
            #pragma unroll
            for (int g = 2; g < 4; ++g)
                #pragma unroll
                for (int ks = 0; ks < 2; ++ks)
                    acc[4 + f][g] = __builtin_amdgcn_mfma_f32_16x16x32_bf16(
                        af[f][ks], bfr[g][ks], acc[4 + f][g], 0, 0, 0);
        __builtin_amdgcn_s_setprio(0);
    }

    #pragma unroll
    for (int f = 0; f < 8; ++f) {
        #pragma unroll
        for (int g = 0; g < 4; ++g) {
            int col = n0 + wn * 64 + g * 16 + (lane & 15);
            #pragma unroll
            for (int rg = 0; rg < 4; ++rg) {
                int row = m0 + wm * 128 + f * 16 + (lane >> 4) * 4 + rg;
                float bb = BIASROW ? bias[row] : bias[col];
                C[(size_t)row * N + col] = acc[f][g][rg] + bb;
            }
        }
    }
}

// ===========================================================================
// Kernel 4: fused q-chain + attn + out_win; emits bf16 Pb (= n_x + res_x_base)
// ===========================================================================
__global__ __launch_bounds__(256) void k_attn(
    const float* __restrict__ P, const float* __restrict__ b_buf, const float* __restrict__ b_rot,
    const float* __restrict__ qpw, const float* __restrict__ qpb,
    const float* __restrict__ nqg, const float* __restrict__ nqb,
    const float* __restrict__ qaw, const float* __restrict__ qab,
    const float* __restrict__ pos, __hip_bfloat16* __restrict__ Pb,
    float* __restrict__ attn_out)
{
    __shared__ float bs[16][4], brs[16][4];
    int t = threadIdx.x;
    int wh = blockIdx.y;
    int wi = wh >> 4, h = wh & 15;
    if (t < 64) {
        ((float*)bs)[t]  = b_buf[wh * 64 + t];
        ((float*)brs)[t] = b_rot[wh * 64 + t];
    }
    __syncthreads();
    int p = blockIdx.x * 256 + t;
    int wr = p >> 8, wc = p & 255;
    int gr = ((wi >> 1) << 8) + wr, gc = ((wi & 1) << 8) + wc;
    int y = gr >> 3, hnr = gr & 7, xq = gc >> 3, wnr = gc & 7;
    size_t base = (size_t)(y * 64 + xq) * 4096 + h * 256 + hnr * 8 + wnr;
    float r[4];
    #pragma unroll
    for (int d = 0; d < 4; ++d) r[d] = P[base + (size_t)d * 64];
    float mu = 0.25f * (r[0] + r[1] + r[2] + r[3]);
    float var = 0.25f * ((r[0]-mu)*(r[0]-mu) + (r[1]-mu)*(r[1]-mu) +
                         (r[2]-mu)*(r[2]-mu) + (r[3]-mu)*(r[3]-mu));
    float inv = rsqrtf(var + 1e-5f);
    float xh[4];
    #pragma unroll
    for (int d = 0; d < 4; ++d) xh[d] = (r[d] - mu) * inv * nqg[d] + nqb[d];
    float q4[4];
    #pragma unroll
    for (int d = 0; d < 4; ++d) {
        float a = qpb[d];
        #pragma unroll
        for (int e = 0; e < 4; ++e) a = fmaf(xh[e], qpw[d * 4 + e], a);
        q4[d] = a;
    }
    float z = qab[0];
    #pragma unroll
    for (int d = 0; d < 4; ++d) z = fmaf(q4[d], qaw[d], z);
    float gate = 1.0f / (1.0f + expf(-z));
    float4 pv = *(const float4*)(pos + ((size_t)h * 65536 + p) * 4);
    float v[4];
    v[0] = q4[0] * gate + pv.x * (1.0f - gate);
    v[1] = q4[1] * gate + pv.y * (1.0f - gate);
    v[2] = q4[2] * gate + pv.z * (1.0f - gate);
    v[3] = q4[3] * gate + pv.w * (1.0f - gate);
    float nn = sqrtf(v[0]*v[0] + v[1]*v[1] + v[2]*v[2] + v[3]*v[3]);
    float in2 = 1.0f / fmaxf(nn, 1e-12f);
    #pragma unroll
    for (int d = 0; d < 4; ++d) v[d] *= in2;
    float s0, c0, s1, c1;
    sincosf((float)wr, &s0, &c0);
    sincosf((float)wc, &s1, &c1);
    float qr[4];
    qr[0] = v[0] * c0 - v[1] * s0;
    qr[1] = v[0] * s0 + v[1] * c0;
    qr[2] = v[2] * c1 - v[3] * s1;
    qr[3] = v[2] * s1 + v[3] * c1;
    float arow[16];
    #pragma unroll
    for (int k = 0; k < 16; ++k)
        arow[k] = qr[0] * brs[k][0] + qr[1] * brs[k][1] + qr[2] * brs[k][2] + qr[3] * brs[k][3];
    size_t abase = ((size_t)wh * 65536 + p) * 16;
    #pragma unroll
    for (int kq = 0; kq < 4; ++kq) {
        float4 av;
        av.x = arow[kq * 4 + 0]; av.y = arow[kq * 4 + 1];
        av.z = arow[kq * 4 + 2]; av.w = arow[kq * 4 + 3];
        *(float4*)(attn_out + abase + kq * 4) = av;
    }
    float o[4] = {0.f, 0.f, 0.f, 0.f};
    #pragma unroll
    for (int k = 0; k < 16; ++k) {
        #pragma unroll
        for (int d = 0; d < 4; ++d) o[d] = fmaf(arow[k], bs[k][d], o[d]);
    }
    #pragma unroll
    for (int d = 0; d < 4; ++d)
        Pb[base + (size_t)d * 64] = __float2bfloat16(r[d] + o[d]);
}

// ===========================================================================
extern "C" void kernel_launch(void* const* d_in, const int* in_sizes, int n_in,
                              void* d_out, int out_size, void* d_ws, size_t ws_size,
                              hipStream_t stream)
{
    (void)in_sizes; (void)n_in; (void)out_size; (void)ws_size;
    const float* x    = (const float*)d_in[0];
    const float* xcw  = (const float*)d_in[1];
    const float* xcb  = (const float*)d_in[2];
    const float* rcw  = (const float*)d_in[3];
    const float* rcb  = (const float*)d_in[4];
    const float* pw   = (const float*)d_in[5];
    const float* pb   = (const float*)d_in[6];
    const float* bpw  = (const float*)d_in[7];
    const float* bpb  = (const float*)d_in[8];
    const float* qpw  = (const float*)d_in[9];
    const float* qpb  = (const float*)d_in[10];
    const float* nbg  = (const float*)d_in[11];
    const float* nbb  = (const float*)d_in[12];
    const float* nqg  = (const float*)d_in[13];
    const float* nqb  = (const float*)d_in[14];
    const float* qaw  = (const float*)d_in[15];
    const float* qab  = (const float*)d_in[16];
    const float* pos  = (const float*)d_in[17];
    const float* prw  = (const float*)d_in[18];
    const float* prb  = (const float*)d_in[19];

    float* ws = (float*)d_ws;
    __hip_bfloat16* Xmb   = (__hip_bfloat16*)d_ws;
    __hip_bfloat16* Cb    = (__hip_bfloat16*)(ws + CB_F);
    float*          biasc = ws + BIASC_F;
    float*          b_buf = ws + BBUF_F;
    float*          b_rot = ws + BROT_F;
    float*          P     = ws + P_F;
    __hip_bfloat16* Pb    = (__hip_bfloat16*)(ws + PB_F);
    __hip_bfloat16* prwb  = (__hip_bfloat16*)(ws + PRWB_F);
    float* out = (float*)d_out;

    k_bchain<<<1, 256, 0, stream>>>(x, xcw, xcb, bpw, bpb, nbg, nbb, b_buf, b_rot);
    k_xmap<<<4096, 256, 0, stream>>>(x, Xmb);
    k_cmat<<<4096, 256, 0, stream>>>(pw, rcw, pb, rcb, Cb, biasc);
    // factorized patch conv: M = s(4096), N = co(4096), K = 1024 (972 real)
    gemm_8p<0><<<dim3(16, 16), 512, 0, stream>>>(Xmb, Cb, biasc, P, 4096, 4096, 1024);
    // fused q-chain / attn / out_win; emits bf16 Pb
    k_attn<<<dim3(256, 64), 256, 0, stream>>>(P, b_buf, b_rot, qpw, qpb, nqg, nqb,
                                              qaw, qab, pos, Pb, out + ATTN_OFF);
    k_cast_bf16<<<16384, 256, 0, stream>>>(prw, prwb, 16777216L);
    // 1x1 proj: M = co(4096), N = s(4096), K = 4096; C = out[co][s], bias per row
    gemm_8p<1><<<dim3(16, 16), 512, 0, stream>>>(prwb, Pb, prb, out, 4096, 4096, 4096);
}

// Round 7
// 512.826 us; speedup vs baseline: 17.0714x; 1.0169x over previous
//
#include <hip/hip_runtime.h>
#include <hip/hip_bf16.h>
#include <math.h>
#include <cstddef>

// ---------------------------------------------------------------------------
// Workspace (float offsets). Total ~151 MB.
//   Xmb   : bf16 [4096 s][1024 k]   floats [0 .. 2,097,152)
//   Cb    : bf16 [4096 co][1024 k]  floats [2,097,152 .. 4,194,304)
//   biasc : f32 [4096]              floats [4,194,304 ..)
//   b_buf : f32 [4096]              floats [4,198,400 ..)
//   b_rot : f32 [4096]              floats [4,202,496 ..)
//   P     : f32 [4096 s][4096 co]   floats [4,206,592 .. 20,983,808)
//   Pb    : bf16 [4096][4096]       floats [20,983,808 .. 29,372,416)
//   prwb  : bf16 [4096][4096]       floats [29,372,416 .. 37,761,024)
// k-index: k = ci*324 + m*18 + n  (ci<3, m<18, n<18; 972 real + 52 zero pad)
// ---------------------------------------------------------------------------
#define CB_F     2097152ull
#define BIASC_F  4194304ull
#define BBUF_F   4198400ull
#define BROT_F   4202496ull
#define P_F      4206592ull
#define PB_F     20983808ull
#define PRWB_F   29372416ull
#define ATTN_OFF 16777216ull

typedef __attribute__((ext_vector_type(8))) short bf16x8;
typedef __attribute__((ext_vector_type(4))) float f32x4;

#define GLOAD16(gsrc, ldst) \
  __builtin_amdgcn_global_load_lds((const __attribute__((address_space(1))) void*)(gsrc), \
                                   (__attribute__((address_space(3))) void*)(ldst), 16, 0, 0)

// ===========================================================================
// Kernel 1: x_feat conv + b-chain (LN, proj, l2, rope)
// ===========================================================================
__global__ __launch_bounds__(256) void k_bchain(
    const float* __restrict__ x, const float* __restrict__ xcw, const float* __restrict__ xcb,
    const float* __restrict__ bpw, const float* __restrict__ bpb,
    const float* __restrict__ nbg, const float* __restrict__ nbb,
    float* __restrict__ b_buf, float* __restrict__ b_rot)
{
    __shared__ float xs[3][8][8];
    __shared__ float xf[64][8][8];
    int t = threadIdx.x;
    if (t < 192) xs[t / 64][(t / 8) % 8][t % 8] = x[t];
    __syncthreads();
    for (int o = t; o < 4096; o += 256) {
        int c = o >> 6, i = (o >> 3) & 7, j = o & 7;
        float acc = xcb[c];
        for (int ic = 0; ic < 3; ++ic)
            for (int ky = 0; ky < 3; ++ky)
                for (int kx = 0; kx < 3; ++kx) {
                    int ii = i - 1 + ky, jj = j - 1 + kx;
                    if (ii >= 0 && ii < 8 && jj >= 0 && jj < 8)
                        acc = fmaf(xs[ic][ii][jj], xcw[((c * 3 + ic) * 3 + ky) * 3 + kx], acc);
                }
        xf[c][i][j] = acc;
    }
    __syncthreads();
    for (int idx = t; idx < 1024; idx += 256) {
        int wi = idx >> 8, h = (idx >> 4) & 15, pp = idx & 15;
        int pr = pp >> 2, pc = pp & 3;
        int gi = 4 * (wi >> 1) + pr, gj = 4 * (wi & 1) + pc;
        float v[4];
        #pragma unroll
        for (int d = 0; d < 4; ++d) v[d] = xf[h * 4 + d][gi][gj];
        float mu = 0.25f * (v[0] + v[1] + v[2] + v[3]);
        float var = 0.25f * ((v[0]-mu)*(v[0]-mu) + (v[1]-mu)*(v[1]-mu) +
                             (v[2]-mu)*(v[2]-mu) + (v[3]-mu)*(v[3]-mu));
        float inv = rsqrtf(var + 1e-5f);
        float xh[4];
        #pragma unroll
        for (int d = 0; d < 4; ++d) xh[d] = (v[d] - mu) * inv * nbg[d] + nbb[d];
        float bv[4];
        #pragma unroll
        for (int d = 0; d < 4; ++d) {
            float a = bpb[d];
            #pragma unroll
            for (int e = 0; e < 4; ++e) a = fmaf(xh[e], bpw[d * 4 + e], a);
            bv[d] = a;
        }
        #pragma unroll
        for (int d = 0; d < 4; ++d) b_buf[idx * 4 + d] = bv[d];
        float nn = sqrtf(bv[0]*bv[0] + bv[1]*bv[1] + bv[2]*bv[2] + bv[3]*bv[3]);
        float in2 = 1.0f / fmaxf(nn, 1e-12f);
        float bn[4];
        #pragma unroll
        for (int d = 0; d < 4; ++d) bn[d] = bv[d] * in2;
        float s0, c0, s1, c1;
        sincosf((float)pr, &s0, &c0);
        sincosf((float)pc, &s1, &c1);
        b_rot[idx * 4 + 0] = bn[0] * c0 - bn[1] * s0;
        b_rot[idx * 4 + 1] = bn[0] * s0 + bn[1] * c0;
        b_rot[idx * 4 + 2] = bn[2] * c1 - bn[3] * s1;
        b_rot[idx * 4 + 3] = bn[2] * s1 + bn[3] * c1;
    }
}

// ===========================================================================
// Kernel 2a: Xmap — A operand of the factorized patch GEMM.
// ===========================================================================
__global__ __launch_bounds__(256) void k_xmap(
    const float* __restrict__ x, __hip_bfloat16* __restrict__ Xmb)
{
    __shared__ float xs[3][8][8];
    int t = threadIdx.x;
    if (t < 192) xs[t / 64][(t / 8) % 8][t % 8] = x[t];
    __syncthreads();
    int s = blockIdx.x, py = s >> 6, px = s & 63;
    __hip_bfloat16 out4[4];
    #pragma unroll
    for (int u = 0; u < 4; ++u) {
        int k = t * 4 + u;
        float val = 0.0f;
        if (k < 972) {
            int ci = k / 324, r = k % 324, m = r / 18, n = r % 18;
            int row = 16 * py + m - 1, col = 16 * px + n - 1;
            if (row >= 0 && row < 1024 && col >= 0 && col < 1024) {
                float fu = (row + 0.5f) * 0.0078125f - 0.5f;
                float fv = (col + 0.5f) * 0.0078125f - 0.5f;
                float fi = floorf(fu), fj = floorf(fv);
                float tu = fu - fi, tv = fv - fj;
                int i0 = (int)fi, j0 = (int)fj;
                int i0c = min(max(i0, 0), 7), i1c = min(max(i0 + 1, 0), 7);
                int j0c = min(max(j0, 0), 7), j1c = min(max(j0 + 1, 0), 7);
                val = (xs[ci][i0c][j0c] * (1.f - tv) + xs[ci][i0c][j1c] * tv) * (1.f - tu)
                    + (xs[ci][i1c][j0c] * (1.f - tv) + xs[ci][i1c][j1c] * tv) * tu;
            }
        }
        out4[u] = __float2bfloat16(val);
    }
    *(ushort4*)(Xmb + (size_t)s * 1024 + t * 4) = *(const ushort4*)out4;
}

// ===========================================================================
// Kernel 2b v3: C matrix. One block per co. Software-pipelined staging
// (next chunk's global loads issue before current compute) + odd-stride
// padded LDS tile (row 21, plane 421 -> all 32 banks, <=2-way).
// C[co,ci,m,n] = sum_{c,ky,kx} rcw[c,ci,ky,kx]*pwpad[m-ky][n-kx]; bias fused.
// ===========================================================================
__global__ __launch_bounds__(256) void k_cmat(
    const float* __restrict__ pw, const float* __restrict__ rcw,
    const float* __restrict__ pb, const float* __restrict__ rcb,
    __hip_bfloat16* __restrict__ Cb, float* __restrict__ biasc)
{
    __shared__ float rcw_s[64 * 28];     // [c][27] padded to 28
    __shared__ float rcb_s[64];
    __shared__ float pwp[8 * 421 + 3];   // word(cl,r,c) = cl*421 + r*21 + c
    __shared__ float red[256];
    int co = blockIdx.x;
    const float* pwc = pw + (size_t)co * 16384;
    int t = threadIdx.x;

    #pragma unroll
    for (int i = 0; i < 7; ++i) {
        int idx = i * 256 + t;
        if (idx < 1728) rcw_s[(idx / 27) * 28 + (idx % 27)] = rcw[idx];
    }
    if (t < 64) rcb_s[t] = rcb[t];
    for (int i = t; i < 8 * 421 + 3; i += 256) pwp[i] = 0.0f;

    int tr = t >> 4, tc = t & 15;        // staging position within 16x16
    int m = t / 9, n0 = (t % 9) * 2;     // compute mapping (t < 162)
    float acc[3][2] = {};
    float bsum = 0.0f;

    // preload chunk 0 into registers
    float rv[8];
    #pragma unroll
    for (int i = 0; i < 8; ++i) rv[i] = pwc[i * 256 + t];

    for (int c0 = 0; c0 < 64; c0 += 8) {
        __syncthreads();                 // prev compute done (first: zero-init done)
        #pragma unroll
        for (int i = 0; i < 8; ++i) {
            pwp[i * 421 + (tr + 2) * 21 + (tc + 2)] = rv[i];
            bsum = fmaf(rcb_s[c0 + i], rv[i], bsum);
        }
        __syncthreads();
        // issue next chunk's loads now; latency hides under compute below
        if (c0 + 8 < 64) {
            #pragma unroll
            for (int i = 0; i < 8; ++i) rv[i] = pwc[(c0 + 8 + i) * 256 + t];
        }
        if (t < 162) {
            #pragma unroll
            for (int cl = 0; cl < 8; ++cl) {
                const float* pp = &pwp[cl * 421];
                float seg[3][4];
                #pragma unroll
                for (int j = 0; j < 3; ++j) {
                    int base = (m + j) * 21 + n0;
                    seg[j][0] = pp[base];     seg[j][1] = pp[base + 1];
                    seg[j][2] = pp[base + 2]; seg[j][3] = pp[base + 3];
                }
                const float* rw = &rcw_s[(c0 + cl) * 28];
                #pragma unroll
                for (int ci = 0; ci < 3; ++ci)
                    #pragma unroll
                    for (int ky = 0; ky < 3; ++ky) {
                        int j = 2 - ky;
                        #pragma unroll
                        for (int kx = 0; kx < 3; ++kx) {
                            float w = rw[ci * 9 + ky * 3 + kx];
                            acc[ci][0] = fmaf(w, seg[j][2 - kx], acc[ci][0]);
                            acc[ci][1] = fmaf(w, seg[j][3 - kx], acc[ci][1]);
                        }
                    }
            }
        }
    }

    // bias reduction
    red[t] = bsum;
    __syncthreads();
    for (int off = 128; off; off >>= 1) {
        if (t < off) red[t] += red[t + off];
        __syncthreads();
    }
    if (t == 0) biasc[co] = pb[co] + red[0];
    // zero padding k in [972,1024)
    if (t >= 162 && t < 214) Cb[(size_t)co * 1024 + 972 + (t - 162)] = __float2bfloat16(0.0f);
    // write outputs
    if (t < 162) {
        size_t cb = (size_t)co * 1024;
        #pragma unroll
        for (int ci = 0; ci < 3; ++ci) {
            Cb[cb + ci * 324 + m * 18 + n0]     = __float2bfloat16(acc[ci][0]);
            Cb[cb + ci * 324 + m * 18 + n0 + 1] = __float2bfloat16(acc[ci][1]);
        }
    }
}

// ===========================================================================
// Cast f32 -> bf16, 8 floats/thread (n divisible by 2048).
// ===========================================================================
__global__ __launch_bounds__(256) void k_cast_bf16(
    const float* __restrict__ in, __hip_bfloat16* __restrict__ out, long n)
{
    long i = ((long)blockIdx.x * 256 + threadIdx.x) * 8;
    if (i >= n) return;
    float4 v0 = *(const float4*)(in + i);
    float4 v1 = *(const float4*)(in + i + 4);
    __hip_bfloat16 h[8] = {__float2bfloat16(v0.x), __float2bfloat16(v0.y),
                           __float2bfloat16(v0.z), __float2bfloat16(v0.w),
                           __float2bfloat16(v1.x), __float2bfloat16(v1.y),
                           __float2bfloat16(v1.z), __float2bfloat16(v1.w)};
    *(ushort4*)(out + i)     = *(const ushort4*)h;
    *(ushort4*)(out + i + 4) = *(const ushort4*)(h + 4);
}

// ===========================================================================
// 8-phase bf16 MFMA NT GEMM (m201 geometry), unchanged.
// ===========================================================================
template <int BIASROW>
__global__ __launch_bounds__(512) void gemm_8p(
    const __hip_bfloat16* __restrict__ A, const __hip_bfloat16* __restrict__ B,
    const float* __restrict__ bias, float* __restrict__ C,
    int M, int N, int K)
{
    __shared__ short lds[65536];
    const short* Ag = (const short*)A;
    const short* Bg = (const short*)B;
    int t = threadIdx.x;
    int lane = t & 63;
    int wid = t >> 6;
    int wm = wid >> 2, wn = wid & 3;

    int nwg = gridDim.x * gridDim.y;
    int flat = blockIdx.y * gridDim.x + blockIdx.x;
    int swz = (flat & 7) * (nwg >> 3) + (flat >> 3);
    int bx = swz % gridDim.x, by = swz / gridDim.x;
    int m0 = by * 256, n0 = bx * 256;
    int T = K >> 6;

    int srow = t >> 3;
    int sc = ((t & 7) ^ (srow & 7)) * 8;
    const short* Asrc[4]; const short* Bsrc[4];
    #pragma unroll
    for (int p = 0; p < 4; ++p) {
        Asrc[p] = Ag + (size_t)(m0 + p * 64 + srow) * K + sc;
        Bsrc[p] = Bg + (size_t)(n0 + p * 64 + srow) * K + sc;
    }

    f32x4 acc[8][4] = {};

    #pragma unroll
    for (int u = 0; u < 2; ++u) {
        short* bA = lds + u * 32768;
        short* bB = bA + 16384;
        size_t ko = (size_t)u * 64;
        #pragma unroll
        for (int p = 0; p < 4; ++p) GLOAD16(Asrc[p] + ko, bA + p * 4096 + t * 8);
        #pragma unroll
        for (int p = 0; p < 4; ++p) GLOAD16(Bsrc[p] + ko, bB + p * 4096 + t * 8);
    }

    for (int tt = 0; tt < T; ++tt) {
        if (tt + 1 < T) { asm volatile("s_waitcnt vmcnt(8)" ::: "memory"); }
        else            { asm volatile("s_waitcnt vmcnt(0)" ::: "memory"); }
        __builtin_amdgcn_s_barrier();
        __builtin_amdgcn_sched_barrier(0);

        const char* Asb = (const char*)(lds + (tt & 1) * 32768);
        const char* Bsb = Asb + 32768;
        short* pA = lds + (tt & 1) * 32768;
        short* pB = pA + 16384;
        bool pf = (tt + 2) < T;
        size_t ko = (size_t)(tt + 2) * 64;

        bf16x8 af[4][2], bfr[4][2];
        // ph0
        #pragma unroll
        for (int f = 0; f < 4; ++f) {
            int r = wm * 128 + f * 16 + (lane & 15);
            #pragma unroll
            for (int ks = 0; ks < 2; ++ks) {
                int cb = ks * 64 + (lane >> 4) * 16;
                af[f][ks] = *(const bf16x8*)(Asb + r * 128 + (cb ^ ((r & 7) << 4)));
            }
        }
        #pragma unroll
        for (int g = 0; g < 2; ++g) {
            int r = wn * 64 + g * 16 + (lane & 15);
            #pragma unroll
            for (int ks = 0; ks < 2; ++ks) {
                int cb = ks * 64 + (lane >> 4) * 16;
                bfr[g][ks] = *(const bf16x8*)(Bsb + r * 128 + (cb ^ ((r & 7) << 4)));
            }
        }
        __builtin_amdgcn_s_barrier();
        __builtin_amdgcn_s_setprio(1);
        #pragma unroll
        for (int f = 0; f < 4; ++f)
            #pragma unroll
            for (int g = 0; g < 2; ++g)
                #pragma unroll
                for (int ks = 0; ks < 2; ++ks)
                    acc[f][g] = __builtin_amdgcn_mfma_f32_16x16x32_bf16(
                        af[f][ks], bfr[g][ks], acc[f][g], 0, 0, 0);
        __builtin_amdgcn_s_setprio(0);
        __builtin_amdgcn_s_barrier();
        // ph1
        #pragma unroll
        for (int g = 2; g < 4; ++g) {
            int r = wn * 64 + g * 16 + (lane & 15);
            #pragma unroll
            for (int ks = 0; ks < 2; ++ks) {
                int cb = ks * 64 + (lane >> 4) * 16;
                bfr[g][ks] = *(const bf16x8*)(Bsb + r * 128 + (cb ^ ((r & 7) << 4)));
            }
        }
        __builtin_amdgcn_s_barrier();
        __builtin_amdgcn_s_setprio(1);
        #pragma unroll
        for (int f = 0; f < 4; ++f)
            #pragma unroll
            for (int g = 2; g < 4; ++g)
                #pragma unroll
                for (int ks = 0; ks < 2; ++ks)
                    acc[f][g] = __builtin_amdgcn_mfma_f32_16x16x32_bf16(
                        af[f][ks], bfr[g][ks], acc[f][g], 0, 0, 0);
        __builtin_amdgcn_s_setprio(0);
        __builtin_amdgcn_s_barrier();
        // ph2
        #pragma unroll
        for (int f = 0; f < 4; ++f) {
            int r = wm * 128 + 64 + f * 16 + (lane & 15);
            #pragma unroll
            for (int ks = 0; ks < 2; ++ks) {
                int cb = ks * 64 + (lane >> 4) * 16;
                af[f][ks] = *(const bf16x8*)(Asb + r * 128 + (cb ^ ((r & 7) << 4)));
            }
        }
        if (pf) {
            #pragma unroll
            for (int p = 0; p < 4; ++p) GLOAD16(Bsrc[p] + ko, pB + p * 4096 + t * 8);
        }
        __builtin_amdgcn_s_barrier();
        __builtin_amdgcn_s_setprio(1);
        #pragma unroll
        for (int f = 0; f < 4; ++f)
            #pragma unroll
            for (int g = 0; g < 2; ++g)
                #pragma unroll
                for (int ks = 0; ks < 2; ++ks)
                    acc[4 + f][g] = __builtin_amdgcn_mfma_f32_16x16x32_bf16(
                        af[f][ks], bfr[g][ks], acc[4 + f][g], 0, 0, 0);
        __builtin_amdgcn_s_setprio(0);
        __builtin_amdgcn_s_barrier();
        // ph3
        if (pf) {
            #pragma unroll
            for (int p = 0; p < 4; ++p) GLOAD16(Asrc[p] + ko, pA + p * 4096 + t * 8);
        }
        __builtin_amdgcn_s_setprio(1);
        #pragma unroll
        for (int f = 0; f < 4; ++f)
            #pragma unroll
            for (int g = 2; g < 4; ++g)
                #pragma unroll
                for (int ks = 0; ks < 2; ++ks)
                    acc[4 + f][g] = __builtin_amdgcn_mfma_f32_16x16x32_bf16(
                        af[f][ks], bfr[g][ks], acc[4 + f][g], 0, 0, 0);
        __builtin_amdgcn_s_setprio(0);
    }

    #pragma unroll
    for (int f = 0; f < 8; ++f) {
        #pragma unroll
        for (int g = 0; g < 4; ++g) {
            int col = n0 + wn * 64 + g * 16 + (lane & 15);
            #pragma unroll
            for (int rg = 0; rg < 4; ++rg) {
                int row = m0 + wm * 128 + f * 16 + (lane >> 4) * 4 + rg;
                float bb = BIASROW ? bias[row] : bias[col];
                C[(size_t)row * N + col] = acc[f][g][rg] + bb;
            }
        }
    }
}

// ===========================================================================
// Kernel 4: fused q-chain + attn + out_win; emits bf16 Pb (= n_x + res_x_base)
// ===========================================================================
__global__ __launch_bounds__(256) void k_attn(
    const float* __restrict__ P, const float* __restrict__ b_buf, const float* __restrict__ b_rot,
    const float* __restrict__ qpw, const float* __restrict__ qpb,
    const float* __restrict__ nqg, const float* __restrict__ nqb,
    const float* __restrict__ qaw, const float* __restrict__ qab,
    const float* __restrict__ pos, __hip_bfloat16* __restrict__ Pb,
    float* __restrict__ attn_out)
{
    __shared__ float bs[16][4], brs[16][4];
    int t = threadIdx.x;
    int wh = blockIdx.y;
    int wi = wh >> 4, h = wh & 15;
    if (t < 64) {
        ((float*)bs)[t]  = b_buf[wh * 64 + t];
        ((float*)brs)[t] = b_rot[wh * 64 + t];
    }
    __syncthreads();
    int p = blockIdx.x * 256 + t;
    int wr = p >> 8, wc = p & 255;
    int gr = ((wi >> 1) << 8) + wr, gc = ((wi & 1) << 8) + wc;
    int y = gr >> 3, hnr = gr & 7, xq = gc >> 3, wnr = gc & 7;
    size_t base = (size_t)(y * 64 + xq) * 4096 + h * 256 + hnr * 8 + wnr;
    float r[4];
    #pragma unroll
    for (int d = 0; d < 4; ++d) r[d] = P[base + (size_t)d * 64];
    float mu = 0.25f * (r[0] + r[1] + r[2] + r[3]);
    float var = 0.25f * ((r[0]-mu)*(r[0]-mu) + (r[1]-mu)*(r[1]-mu) +
                         (r[2]-mu)*(r[2]-mu) + (r[3]-mu)*(r[3]-mu));
    float inv = rsqrtf(var + 1e-5f);
    float xh[4];
    #pragma unroll
    for (int d = 0; d < 4; ++d) xh[d] = (r[d] - mu) * inv * nqg[d] + nqb[d];
    float q4[4];
    #pragma unroll
    for (int d = 0; d < 4; ++d) {
        float a = qpb[d];
        #pragma unroll
        for (int e = 0; e < 4; ++e) a = fmaf(xh[e], qpw[d * 4 + e], a);
        q4[d] = a;
    }
    float z = qab[0];
    #pragma unroll
    for (int d = 0; d < 4; ++d) z = fmaf(q4[d], qaw[d], z);
    float gate = 1.0f / (1.0f + expf(-z));
    float4 pv = *(const float4*)(pos + ((size_t)h * 65536 + p) * 4);
    float v[4];
    v[0] = q4[0] * gate + pv.x * (1.0f - gate);
    v[1] = q4[1] * gate + pv.y * (1.0f - gate);
    v[2] = q4[2] * gate + pv.z * (1.0f - gate);
    v[3] = q4[3] * gate + pv.w * (1.0f - gate);
    float nn = sqrtf(v[0]*v[0] + v[1]*v[1] + v[2]*v[2] + v[3]*v[3]);
    float in2 = 1.0f / fmaxf(nn, 1e-12f);
    #pragma unroll
    for (int d = 0; d < 4; ++d) v[d] *= in2;
    float s0, c0, s1, c1;
    sincosf((float)wr, &s0, &c0);
    sincosf((float)wc, &s1, &c1);
    float qr[4];
    qr[0] = v[0] * c0 - v[1] * s0;
    qr[1] = v[0] * s0 + v[1] * c0;
    qr[2] = v[2] * c1 - v[3] * s1;
    qr[3] = v[2] * s1 + v[3] * c1;
    float arow[16];
    #pragma unroll
    for (int k = 0; k < 16; ++k)
        arow[k] = qr[0] * brs[k][0] + qr[1] * brs[k][1] + qr[2] * brs[k][2] + qr[3] * brs[k][3];
    size_t abase = ((size_t)wh * 65536 + p) * 16;
    #pragma unroll
    for (int kq = 0; kq < 4; ++kq) {
        float4 av;
        av.x = arow[kq * 4 + 0]; av.y = arow[kq * 4 + 1];
        av.z = arow[kq * 4 + 2]; av.w = arow[kq * 4 + 3];
        *(float4*)(attn_out + abase + kq * 4) = av;
    }
    float o[4] = {0.f, 0.f, 0.f, 0.f};
    #pragma unroll
    for (int k = 0; k < 16; ++k) {
        #pragma unroll
        for (int d = 0; d < 4; ++d) o[d] = fmaf(arow[k], bs[k][d], o[d]);
    }
    #pragma unroll
    for (int d = 0; d < 4; ++d)
        Pb[base + (size_t)d * 64] = __float2bfloat16(r[d] + o[d]);
}

// ===========================================================================
extern "C" void kernel_launch(void* const* d_in, const int* in_sizes, int n_in,
                              void* d_out, int out_size, void* d_ws, size_t ws_size,
                              hipStream_t stream)
{
    (void)in_sizes; (void)n_in; (void)out_size; (void)ws_size;
    const float* x    = (const float*)d_in[0];
    const float* xcw  = (const float*)d_in[1];
    const float* xcb  = (const float*)d_in[2];
    const float* rcw  = (const float*)d_in[3];
    const float* rcb  = (const float*)d_in[4];
    const float* pw   = (const float*)d_in[5];
    const float* pb   = (const float*)d_in[6];
    const float* bpw  = (const float*)d_in[7];
    const float* bpb  = (const float*)d_in[8];
    const float* qpw  = (const float*)d_in[9];
    const float* qpb  = (const float*)d_in[10];
    const float* nbg  = (const float*)d_in[11];
    const float* nbb  = (const float*)d_in[12];
    const float* nqg  = (const float*)d_in[13];
    const float* nqb  = (const float*)d_in[14];
    const float* qaw  = (const float*)d_in[15];
    const float* qab  = (const float*)d_in[16];
    const float* pos  = (const float*)d_in[17];
    const float* prw  = (const float*)d_in[18];
    const float* prb  = (const float*)d_in[19];

    float* ws = (float*)d_ws;
    __hip_bfloat16* Xmb   = (__hip_bfloat16*)d_ws;
    __hip_bfloat16* Cb    = (__hip_bfloat16*)(ws + CB_F);
    float*          biasc = ws + BIASC_F;
    float*          b_buf = ws + BBUF_F;
    float*          b_rot = ws + BROT_F;
    float*          P     = ws + P_F;
    __hip_bfloat16* Pb    = (__hip_bfloat16*)(ws + PB_F);
    __hip_bfloat16* prwb  = (__hip_bfloat16*)(ws + PRWB_F);
    float* out = (float*)d_out;

    k_bchain<<<1, 256, 0, stream>>>(x, xcw, xcb, bpw, bpb, nbg, nbb, b_buf, b_rot);
    k_xmap<<<4096, 256, 0, stream>>>(x, Xmb);
    k_cmat<<<4096, 256, 0, stream>>>(pw, rcw, pb, rcb, Cb, biasc);
    // factorized patch conv: M = s(4096), N = co(4096), K = 1024 (972 real)
    gemm_8p<0><<<dim3(16, 16), 512, 0, stream>>>(Xmb, Cb, biasc, P, 4096, 4096, 1024);
    // fused q-chain / attn / out_win; emits bf16 Pb
    k_attn<<<dim3(256, 64), 256, 0, stream>>>(P, b_buf, b_rot, qpw, qpb, nqg, nqb,
                                              qaw, qab, pos, Pb, out + ATTN_OFF);
    k_cast_bf16<<<8192, 256, 0, stream>>>(prw, prwb, 16777216L);
    // 1x1 proj: M = co(4096), N = s(4096), K = 4096; C = out[co][s], bias per row
    gemm_8p<1><<<dim3(16, 16), 512, 0, stream>>>(prwb, Pb, prb, out, 4096, 4096, 4096);
}